// Round 4
// baseline (494.311 us; speedup 1.0000x reference)
//
#include <hip/hip_runtime.h>

// Problem constants
static constexpr int kBS    = 8;
static constexpr int kNROI  = 128;
static constexpr int kR     = kBS * kNROI;   // 1024 rows
static constexpr int kCH    = 1280;
static constexpr int kH     = 64;
static constexpr int kW     = 64;
static constexpr int kPIX   = kH * kW;       // 4096
static constexpr int kINNER = 5120;
static constexpr int kOUTC  = 1024;
static constexpr int kXE    = 2 * kOUTC;     // 2048 concat width
static constexpr int kE2    = 256;           // size-MLP hidden 2

typedef _Float16 half8 __attribute__((ext_vector_type(8)));   // f16x8 MFMA A/B frag
typedef float floatx4 __attribute__((ext_vector_type(4)));    // MFMA C/D frag

// Async global->LDS 16B copy. LDS dest must be wave-uniform base + lane*16,
// which our chunk-index==threadIdx staging layout satisfies exactly.
__device__ __forceinline__ void gload_lds16(const _Float16* g, _Float16* l) {
    __builtin_amdgcn_global_load_lds(
        (const __attribute__((address_space(1))) void*)g,
        (__attribute__((address_space(3))) void*)l,
        16, 0, 0);
}

// ---------------------------------------------------------------------------
// Transpose+convert z: (b, c, H*W) fp32 -> zt: (b, H*W, c) f16
// ---------------------------------------------------------------------------
__global__ __launch_bounds__(256) void transpose_z_f16(const float* __restrict__ z,
                                                       _Float16* __restrict__ zt) {
    __shared__ float tile[64][33];   // [c_local][p_local]
    const int b  = blockIdx.z;
    const int p0 = blockIdx.x * 32;
    const int c0 = blockIdx.y * 64;
    const int tx = threadIdx.x;      // 0..31
    const int ty = threadIdx.y;      // 0..7
    const float* zb = z + (size_t)b * kCH * kPIX;
    _Float16* ztb = zt + (size_t)b * kPIX * kCH;
#pragma unroll
    for (int i = 0; i < 8; ++i) {
        const int cl = ty + i * 8;   // 0..63
        tile[cl][tx] = zb[(size_t)(c0 + cl) * kPIX + p0 + tx];
    }
    __syncthreads();
#pragma unroll
    for (int i = 0; i < 4; ++i) {
        const int pl = ty + i * 8;   // 0..31
        union { _Float16 h[2]; unsigned int u; } pk;
        pk.h[0] = (_Float16)tile[2 * tx][pl];
        pk.h[1] = (_Float16)tile[2 * tx + 1][pl];
        *(unsigned int*)(ztb + (size_t)(p0 + pl) * kCH + c0 + 2 * tx) = pk.u;
    }
}

// ---------------------------------------------------------------------------
// ROI point lists (separable bilinear weights)
// ---------------------------------------------------------------------------
struct RoiLists {
    int   yidx[16], xidx[16];
    float ywt[16], xwt[16];
    int   ny, nx;
    float invCount;
};

__device__ inline void build_lists(const float* __restrict__ bboxes, int r, RoiLists* L) {
    const float x1 = bboxes[r * 4 + 0] * 0.125f - 0.5f;
    const float y1 = bboxes[r * 4 + 1] * 0.125f - 0.5f;
    const float x2 = bboxes[r * 4 + 2] * 0.125f - 0.5f;
    const float y2 = bboxes[r * 4 + 3] * 0.125f - 0.5f;
    const float rw = x2 - x1, rh = y2 - y1;
    const float gwf = fminf(fmaxf(ceilf(rw), 1.0f), 8.0f);
    const float ghf = fminf(fmaxf(ceilf(rh), 1.0f), 8.0f);
    const int gw = (int)gwf, gh = (int)ghf;
    L->invCount = 1.0f / (gwf * ghf);
    for (int g = 0; g < gh; ++g) {
        const float c   = y1 + ((float)g + 0.5f) * rh / ghf;
        const bool oob  = (c < -1.0f) || (c > 64.0f);
        const float cc  = fmaxf(c, 0.0f);
        const float lo0 = floorf(cc);
        const bool hic  = (lo0 >= 63.0f);
        const int lo    = (int)fminf(lo0, 63.0f);
        const int hi    = (int)fminf(lo0 + 1.0f, 63.0f);
        const float fr  = hic ? 0.0f : (cc - lo0);
        const float m   = oob ? 0.0f : 1.0f;
        L->yidx[2 * g]     = lo; L->ywt[2 * g]     = m * (1.0f - fr);
        L->yidx[2 * g + 1] = hi; L->ywt[2 * g + 1] = m * fr;
    }
    L->ny = 2 * gh;
    for (int g = 0; g < gw; ++g) {
        const float c   = x1 + ((float)g + 0.5f) * rw / gwf;
        const bool oob  = (c < -1.0f) || (c > 64.0f);
        const float cc  = fmaxf(c, 0.0f);
        const float lo0 = floorf(cc);
        const bool hic  = (lo0 >= 63.0f);
        const int lo    = (int)fminf(lo0, 63.0f);
        const int hi    = (int)fminf(lo0 + 1.0f, 63.0f);
        const float fr  = hic ? 0.0f : (cc - lo0);
        const float m   = oob ? 0.0f : 1.0f;
        L->xidx[2 * g]     = lo; L->xwt[2 * g]     = m * (1.0f - fr);
        L->xidx[2 * g + 1] = hi; L->xwt[2 * g + 1] = m * fr;
    }
    L->nx = 2 * gw;
}

// ---------------------------------------------------------------------------
// ROI gather v2 from channels-last f16 zt -> f16 x (1024 x 1280).
// Grid (5, kR): blockIdx.x = 32-chunk channel group, blockIdx.y = ROI.
// ---------------------------------------------------------------------------
__global__ __launch_bounds__(256) void roi_gather_f16_v2(const _Float16* __restrict__ zt,
                                                         const float* __restrict__ bboxes,
                                                         _Float16* __restrict__ x) {
    const int r  = blockIdx.y;
    const int b  = r >> 7;
    const int cg = blockIdx.x * 32;    // base chunk (c8 units) of this block
    const int t  = threadIdx.x;
    __shared__ RoiLists L;
    __shared__ int   off[256];
    __shared__ float wt[256];
    __shared__ float accs[8][32][9];   // [pg][chunk][ch] (+1 pad col)
    if (t == 0) build_lists(bboxes, r, &L);
    __syncthreads();
    const int np = L.ny * L.nx;        // <= 256
    if (t < np) {
        const int iy = t / L.nx;
        const int ix = t - iy * L.nx;
        off[t] = (L.yidx[iy] * kW + L.xidx[ix]) * kCH;
        wt[t]  = L.ywt[iy] * L.xwt[ix];
    }
    __syncthreads();
    const int lc = t & 31;
    const int pg = t >> 5;
    const _Float16* base = zt + (size_t)b * kPIX * kCH + (size_t)(cg + lc) * 8;
    float a[8] = {0.f, 0.f, 0.f, 0.f, 0.f, 0.f, 0.f, 0.f};
    for (int p = pg; p < np; p += 8) {
        const float w = wt[p];
        const half8 v = *(const half8*)(base + off[p]);
#pragma unroll
        for (int q = 0; q < 8; ++q) a[q] += w * (float)v[q];
    }
#pragma unroll
    for (int q = 0; q < 8; ++q) accs[pg][lc][q] = a[q];
    __syncthreads();
    // reduce: thread t -> chunk rc = t>>3, channel ch = t&7 (contiguous store)
    const int rc = t >> 3, ch = t & 7;
    float s = 0.f;
#pragma unroll
    for (int g = 0; g < 8; ++g) s += accs[g][rc][ch];
    x[(size_t)r * kCH + (size_t)(cg + rc) * 8 + ch] = (_Float16)(s * L.invCount);
}

// Fallback: gather directly from fp32 z (b,c,H,W) -> f16 x
__global__ __launch_bounds__(256) void roi_gather_direct(const float* __restrict__ z,
                                                         const float* __restrict__ bboxes,
                                                         _Float16* __restrict__ x) {
    const int r = blockIdx.x;
    const int b = r >> 7;
    __shared__ RoiLists L;
    if (threadIdx.x == 0) build_lists(bboxes, r, &L);
    __syncthreads();
    const int ny = L.ny, nx = L.nx;
    const float ic = L.invCount;
    const float* zb = z + (size_t)b * kCH * kPIX;
    for (int c = threadIdx.x; c < kCH; c += 256) {
        const float* zc = zb + (size_t)c * kPIX;
        float acc = 0.f;
        for (int iy = 0; iy < ny; ++iy) {
            const float wy = L.ywt[iy];
            const int base = L.yidx[iy] * kW;
            for (int ix = 0; ix < nx; ++ix)
                acc += wy * L.xwt[ix] * zc[base + L.xidx[ix]];
        }
        x[(size_t)r * kCH + c] = (_Float16)(acc * ic);
    }
}

// ---------------------------------------------------------------------------
// ALL weight transposes+converts in ONE launch (saves 3 dispatch gaps).
// Tile ranges: W1 (1280x5120): 6400 tiles; W2 (5120x1024): 5120;
// O (2048x1024): 2048; S3 (256x1024): 256. Total 13824 blocks of (32,8).
// ---------------------------------------------------------------------------
__global__ __launch_bounds__(256) void convert_all(const float* __restrict__ W1,
                                                   const float* __restrict__ W2,
                                                   const float* __restrict__ O,
                                                   const float* __restrict__ S3,
                                                   _Float16* __restrict__ W1t,
                                                   _Float16* __restrict__ W2t,
                                                   _Float16* __restrict__ Ot,
                                                   _Float16* __restrict__ S3t) {
    const int bid = blockIdx.x;
    const float* W; _Float16* Wt; int K, N, tile;
    if (bid < 6400)        { W = W1; Wt = W1t; K = kCH;    N = kINNER; tile = bid; }
    else if (bid < 11520)  { W = W2; Wt = W2t; K = kINNER; N = kOUTC;  tile = bid - 6400; }
    else if (bid < 13568)  { W = O;  Wt = Ot;  K = kXE;    N = kOUTC;  tile = bid - 11520; }
    else                   { W = S3; Wt = S3t; K = kE2;    N = kOUTC;  tile = bid - 13568; }
    const int nt = N / 32;
    const int n0 = (tile % nt) * 32;
    const int k0 = (tile / nt) * 32;
    __shared__ float tilebuf[32][33];  // [k][n]
    const int tx = threadIdx.x;     // 0..31
    const int ty = threadIdx.y;     // 0..7
#pragma unroll
    for (int i = 0; i < 4; ++i)
        tilebuf[ty + i * 8][tx] = W[(size_t)(k0 + ty + i * 8) * N + n0 + tx];
    __syncthreads();
#pragma unroll
    for (int i = 0; i < 4; ++i)
        Wt[(size_t)(n0 + ty + i * 8) * K + k0 + tx] = (_Float16)tilebuf[tx][ty + i * 8];
}

// ---------------------------------------------------------------------------
// Fused f16 MFMA GEMM (NT), BM x BN tile, BK=32, 256 threads = 4 waves
// (2x2 wave grid). Double-buffered global_load_lds staging. Epilogue adds
// bias (+ReLU) and stores f16/f32 at ldc. No split-K, no partial buffer.
// A: M x Kfull (row-major), Bt: N x Kfull (row-major).
// ---------------------------------------------------------------------------
template <int BM, int BN, bool RELU, bool F16OUT>
__global__ __launch_bounds__(256) void gemm_fused(const _Float16* __restrict__ A,
                                                  const _Float16* __restrict__ Bt,
                                                  const float* __restrict__ bias,
                                                  void* __restrict__ Out,
                                                  int Kfull, int ldc) {
    constexpr int ACH = BM * 4;          // 16B chunks per A k-tile
    constexpr int BCH = BN * 4;          // 16B chunks per B k-tile
    constexpr int FI  = BM / 32;         // fragment rows per wave
    constexpr int FJ  = BN / 32;         // fragment cols per wave
    __shared__ _Float16 As[2][BM * 32];  // [buf][m][k] row-major, chunk c at [c*8]
    __shared__ _Float16 Bs[2][BN * 32];  // [buf][n][k] row-major
    const int t    = threadIdx.x;
    const int lane = t & 63;
    const int wave = t >> 6;
    const int m0 = blockIdx.y * BM, n0 = blockIdx.x * BN;

    const int wm = (wave >> 1) * (BM / 2);  // wave row offset in tile
    const int wn = (wave & 1) * (BN / 2);   // wave col offset in tile
    const int fm = lane & 15;               // fragment row/col within 16
    const int kq = (lane >> 4) * 8;         // fragment k offset

    auto stage = [&](int buf, int kk) {
#pragma unroll
        for (int cc = t; cc < ACH; cc += 256)
            gload_lds16(A + (size_t)(m0 + (cc >> 2)) * Kfull + (cc & 3) * 8 + kk,
                        &As[buf][cc * 8]);
#pragma unroll
        for (int cc = t; cc < BCH; cc += 256)
            gload_lds16(Bt + (size_t)(n0 + (cc >> 2)) * Kfull + (cc & 3) * 8 + kk,
                        &Bs[buf][cc * 8]);
    };

    floatx4 acc[FI][FJ];
#pragma unroll
    for (int i = 0; i < FI; ++i)
#pragma unroll
        for (int j = 0; j < FJ; ++j) acc[i][j] = (floatx4){0.f, 0.f, 0.f, 0.f};

    const int nsteps = Kfull / 32;
    stage(0, 0);
    __syncthreads();

    for (int ks = 0; ks < nsteps; ++ks) {
        const int cur = ks & 1;
        if (ks + 1 < nsteps) stage(cur ^ 1, (ks + 1) * 32);
        half8 af[FI], bfv[FJ];
#pragma unroll
        for (int i = 0; i < FI; ++i)
            af[i] = *(const half8*)&As[cur][(wm + i * 16 + fm) * 32 + kq];
#pragma unroll
        for (int j = 0; j < FJ; ++j)
            bfv[j] = *(const half8*)&Bs[cur][(wn + j * 16 + fm) * 32 + kq];
#pragma unroll
        for (int i = 0; i < FI; ++i)
#pragma unroll
            for (int j = 0; j < FJ; ++j)
                acc[i][j] = __builtin_amdgcn_mfma_f32_16x16x32_f16(af[i], bfv[j], acc[i][j], 0, 0, 0);
        __syncthreads();
    }

    // Epilogue. C/D layout: col = lane&15, row = (lane>>4)*4 + rr
    const int qr = (lane >> 4) * 4;
#pragma unroll
    for (int j = 0; j < FJ; ++j) {
        const int col = n0 + wn + j * 16 + fm;
        const float bv = bias[col];
#pragma unroll
        for (int i = 0; i < FI; ++i) {
            const int row = m0 + wm + i * 16 + qr;
#pragma unroll
            for (int rr = 0; rr < 4; ++rr) {
                float v = acc[i][j][rr] + bv;
                if (RELU) v = fmaxf(v, 0.f);
                if (F16OUT)
                    ((_Float16*)Out)[(size_t)(row + rr) * ldc + col] = (_Float16)v;
                else
                    ((float*)Out)[(size_t)(row + rr) * ldc + col] = v;
            }
        }
    }
}

// ---------------------------------------------------------------------------
// Size-embedding MLP layers 1+2: 2 -> 64 -> 256, f16 out (kR x 256).
// 4 rows per block, 256 blocks -> full CU coverage. Layer 3 runs on MFMA.
// ---------------------------------------------------------------------------
__global__ __launch_bounds__(256) void size_mlp12(const float* __restrict__ bboxes,
                                                  const float* __restrict__ S1,
                                                  const float* __restrict__ sb1,
                                                  const float* __restrict__ S2,
                                                  const float* __restrict__ sb2,
                                                  _Float16* __restrict__ h2out) {
    const int r0 = blockIdx.x * 4;
    const int t  = threadIdx.x;
    __shared__ float sz[4][2];     // [row][{h,w}]
    __shared__ float h1[4][64];
    if (t < 8) {
        const int row = t >> 1;
        const int c   = t & 1;
        const float* bb = bboxes + (size_t)(r0 + row) * 4;
        sz[row][c] = (c == 0) ? (bb[3] - bb[1]) : (bb[2] - bb[0]);
    }
    __syncthreads();
    {   // layer 1: 4 rows x 64 = 256 items, one per thread
        const int row = t >> 6;
        const int j   = t & 63;
        const float v = sz[row][0] * S1[j] + sz[row][1] * S1[64 + j] + sb1[j];
        h1[row][j] = fmaxf(v, 0.0f);
    }
    __syncthreads();
    {   // layer 2: j = t, 4 rows register-blocked
        float acc[4];
        const float b = sb2[t];
#pragma unroll
        for (int row = 0; row < 4; ++row) acc[row] = b;
#pragma unroll 16
        for (int k = 0; k < 64; ++k) {
            const float w = S2[k * 256 + t];
#pragma unroll
            for (int row = 0; row < 4; ++row) acc[row] += h1[row][k] * w;
        }
#pragma unroll
        for (int row = 0; row < 4; ++row)
            h2out[(size_t)(r0 + row) * kE2 + t] = (_Float16)fmaxf(acc[row], 0.0f);
    }
}

// ---------------------------------------------------------------------------
extern "C" void kernel_launch(void* const* d_in, const int* in_sizes, int n_in,
                              void* d_out, int out_size, void* d_ws, size_t ws_size,
                              hipStream_t stream) {
    (void)in_sizes; (void)n_in; (void)out_size;
    const float* z   = (const float*)d_in[0];
    const float* bb  = (const float*)d_in[1];
    const float* W1  = (const float*)d_in[2];
    const float* b1  = (const float*)d_in[3];
    const float* W2  = (const float*)d_in[4];
    const float* b2  = (const float*)d_in[5];
    const float* S1  = (const float*)d_in[6];
    const float* sb1 = (const float*)d_in[7];
    const float* S2  = (const float*)d_in[8];
    const float* sb2 = (const float*)d_in[9];
    const float* S3  = (const float*)d_in[10];
    const float* sb3 = (const float*)d_in[11];
    const float* O   = (const float*)d_in[12];
    const float* ob  = (const float*)d_in[13];
    float* out = (float*)d_out;

    char* ws = (char*)d_ws;
    size_t off = 0;
    auto alloc = [&](size_t bytes) {
        void* p = ws + off;
        off += (bytes + 255) & ~(size_t)255;
        return p;
    };
    _Float16* x    = (_Float16*)alloc((size_t)kR * kCH * 2);        //  2.6 MB
    _Float16* h    = (_Float16*)alloc((size_t)kR * kINNER * 2);     // 10.5 MB
    _Float16* xe   = (_Float16*)alloc((size_t)kR * kXE * 2);        //  4.2 MB
    _Float16* W1t  = (_Float16*)alloc((size_t)kINNER * kCH * 2);    // 13.1 MB
    _Float16* W2t  = (_Float16*)alloc((size_t)kOUTC * kINNER * 2);  // 10.5 MB
    _Float16* Ot   = (_Float16*)alloc((size_t)kOUTC * kXE * 2);     //  4.2 MB
    _Float16* S3t  = (_Float16*)alloc((size_t)kOUTC * kE2 * 2);     //  0.5 MB
    _Float16* h2f  = (_Float16*)alloc((size_t)kR * kE2 * 2);        //  0.5 MB
    const size_t ztBytes = (size_t)kBS * kPIX * kCH * 2;            // 83.9 MB
    _Float16* zt  = (_Float16*)(ws + off);
    const bool useT = (off + ztBytes) <= ws_size;

    // 0) all weight conversions in one launch
    hipLaunchKernelGGL(convert_all, dim3(13824), dim3(32, 8), 0, stream,
                       W1, W2, O, S3, W1t, W2t, Ot, S3t);

    // 1) ROI-align features -> x (1024 x 1280 f16)
    if (useT) {
        hipLaunchKernelGGL(transpose_z_f16, dim3(kPIX / 32, kCH / 64, kBS), dim3(32, 8), 0,
                           stream, z, zt);
        hipLaunchKernelGGL(roi_gather_f16_v2, dim3(kCH / 256, kR), dim3(256), 0, stream,
                           zt, bb, x);
    } else {
        hipLaunchKernelGGL(roi_gather_direct, dim3(kR), dim3(256), 0, stream, z, bb, x);
    }

    // 2) size-embedding MLP layers 1+2 -> h2f (1024 x 256 f16)
    hipLaunchKernelGGL(size_mlp12, dim3(kR / 4), dim3(256), 0, stream,
                       bb, S1, sb1, S2, sb2, h2f);
    // 2b) layer 3 on MFMA, fused: xe[:, 1024:2048] = h2f @ S3 + sb3 (256 blocks)
    hipLaunchKernelGGL((gemm_fused<64, 64, false, true>),
                       dim3(kOUTC / 64, kR / 64), dim3(256), 0, stream,
                       h2f, S3t, sb3, xe + kOUTC, kE2, kXE);

    // 3) h = relu(x @ W1 + b1): (1024x1280)@(1280x5120), fused, 320 blocks
    hipLaunchKernelGGL((gemm_fused<128, 128, true, true>),
                       dim3(kINNER / 128, kR / 128), dim3(256), 0, stream,
                       x, W1t, b1, h, kCH, kINNER);

    // 4) xe[:, 0:1024] = h @ W2 + b2: (1024x5120)@(5120x1024), fused 64x64, 256 blocks
    hipLaunchKernelGGL((gemm_fused<64, 64, false, true>),
                       dim3(kOUTC / 64, kR / 64), dim3(256), 0, stream,
                       h, W2t, b2, xe, kINNER, kXE);

    // 5) out = xe @ O + ob: (1024x2048)@(2048x1024), fused 64x64, 256 blocks
    hipLaunchKernelGGL((gemm_fused<64, 64, false, false>),
                       dim3(kOUTC / 64, kR / 64), dim3(256), 0, stream,
                       xe, Ot, ob, out, kXE, kOUTC);
}

// Round 5
// 440.014 us; speedup vs baseline: 1.1234x; 1.1234x over previous
//
#include <hip/hip_runtime.h>

// Problem constants
static constexpr int kBS    = 8;
static constexpr int kNROI  = 128;
static constexpr int kR     = kBS * kNROI;   // 1024 rows
static constexpr int kCH    = 1280;
static constexpr int kH     = 64;
static constexpr int kW     = 64;
static constexpr int kPIX   = kH * kW;       // 4096
static constexpr int kINNER = 5120;
static constexpr int kOUTC  = 1024;
static constexpr int kXE    = 2 * kOUTC;     // 2048 concat width
static constexpr int kE2    = 256;           // size-MLP hidden 2

typedef _Float16 half8 __attribute__((ext_vector_type(8)));   // f16x8 MFMA A/B frag
typedef float floatx4 __attribute__((ext_vector_type(4)));    // MFMA C/D frag

// Async global->LDS 16B copy. LDS dest must be wave-uniform base + lane*16,
// which our chunk-index==threadIdx staging layout satisfies exactly.
__device__ __forceinline__ void gload_lds16(const _Float16* g, _Float16* l) {
    __builtin_amdgcn_global_load_lds(
        (const __attribute__((address_space(1))) void*)g,
        (__attribute__((address_space(3))) void*)l,
        16, 0, 0);
}

// ---------------------------------------------------------------------------
// Transpose+convert z: (b, c, H*W) fp32 -> zt: (b, H*W, c) f16
// ---------------------------------------------------------------------------
__global__ __launch_bounds__(256) void transpose_z_f16(const float* __restrict__ z,
                                                       _Float16* __restrict__ zt) {
    __shared__ float tile[64][33];   // [c_local][p_local]
    const int b  = blockIdx.z;
    const int p0 = blockIdx.x * 32;
    const int c0 = blockIdx.y * 64;
    const int tx = threadIdx.x;      // 0..31
    const int ty = threadIdx.y;      // 0..7
    const float* zb = z + (size_t)b * kCH * kPIX;
    _Float16* ztb = zt + (size_t)b * kPIX * kCH;
#pragma unroll
    for (int i = 0; i < 8; ++i) {
        const int cl = ty + i * 8;   // 0..63
        tile[cl][tx] = zb[(size_t)(c0 + cl) * kPIX + p0 + tx];
    }
    __syncthreads();
#pragma unroll
    for (int i = 0; i < 4; ++i) {
        const int pl = ty + i * 8;   // 0..31
        union { _Float16 h[2]; unsigned int u; } pk;
        pk.h[0] = (_Float16)tile[2 * tx][pl];
        pk.h[1] = (_Float16)tile[2 * tx + 1][pl];
        *(unsigned int*)(ztb + (size_t)(p0 + pl) * kCH + c0 + 2 * tx) = pk.u;
    }
}

// ---------------------------------------------------------------------------
// ROI point lists (separable bilinear weights)
// ---------------------------------------------------------------------------
struct RoiLists {
    int   yidx[16], xidx[16];
    float ywt[16], xwt[16];
    int   ny, nx;
    float invCount;
};

__device__ inline void build_lists(const float* __restrict__ bboxes, int r, RoiLists* L) {
    const float x1 = bboxes[r * 4 + 0] * 0.125f - 0.5f;
    const float y1 = bboxes[r * 4 + 1] * 0.125f - 0.5f;
    const float x2 = bboxes[r * 4 + 2] * 0.125f - 0.5f;
    const float y2 = bboxes[r * 4 + 3] * 0.125f - 0.5f;
    const float rw = x2 - x1, rh = y2 - y1;
    const float gwf = fminf(fmaxf(ceilf(rw), 1.0f), 8.0f);
    const float ghf = fminf(fmaxf(ceilf(rh), 1.0f), 8.0f);
    const int gw = (int)gwf, gh = (int)ghf;
    L->invCount = 1.0f / (gwf * ghf);
    for (int g = 0; g < gh; ++g) {
        const float c   = y1 + ((float)g + 0.5f) * rh / ghf;
        const bool oob  = (c < -1.0f) || (c > 64.0f);
        const float cc  = fmaxf(c, 0.0f);
        const float lo0 = floorf(cc);
        const bool hic  = (lo0 >= 63.0f);
        const int lo    = (int)fminf(lo0, 63.0f);
        const int hi    = (int)fminf(lo0 + 1.0f, 63.0f);
        const float fr  = hic ? 0.0f : (cc - lo0);
        const float m   = oob ? 0.0f : 1.0f;
        L->yidx[2 * g]     = lo; L->ywt[2 * g]     = m * (1.0f - fr);
        L->yidx[2 * g + 1] = hi; L->ywt[2 * g + 1] = m * fr;
    }
    L->ny = 2 * gh;
    for (int g = 0; g < gw; ++g) {
        const float c   = x1 + ((float)g + 0.5f) * rw / gwf;
        const bool oob  = (c < -1.0f) || (c > 64.0f);
        const float cc  = fmaxf(c, 0.0f);
        const float lo0 = floorf(cc);
        const bool hic  = (lo0 >= 63.0f);
        const int lo    = (int)fminf(lo0, 63.0f);
        const int hi    = (int)fminf(lo0 + 1.0f, 63.0f);
        const float fr  = hic ? 0.0f : (cc - lo0);
        const float m   = oob ? 0.0f : 1.0f;
        L->xidx[2 * g]     = lo; L->xwt[2 * g]     = m * (1.0f - fr);
        L->xidx[2 * g + 1] = hi; L->xwt[2 * g + 1] = m * fr;
    }
    L->nx = 2 * gw;
}

// ---------------------------------------------------------------------------
// ROI gather v2 from channels-last f16 zt -> f16 x (1024 x 1280).
// Grid (5, kR): blockIdx.x = 32-chunk channel group, blockIdx.y = ROI.
// ---------------------------------------------------------------------------
__global__ __launch_bounds__(256) void roi_gather_f16_v2(const _Float16* __restrict__ zt,
                                                         const float* __restrict__ bboxes,
                                                         _Float16* __restrict__ x) {
    const int r  = blockIdx.y;
    const int b  = r >> 7;
    const int cg = blockIdx.x * 32;    // base chunk (c8 units) of this block
    const int t  = threadIdx.x;
    __shared__ RoiLists L;
    __shared__ int   off[256];
    __shared__ float wt[256];
    __shared__ float accs[8][32][9];   // [pg][chunk][ch] (+1 pad col)
    if (t == 0) build_lists(bboxes, r, &L);
    __syncthreads();
    const int np = L.ny * L.nx;        // <= 256
    if (t < np) {
        const int iy = t / L.nx;
        const int ix = t - iy * L.nx;
        off[t] = (L.yidx[iy] * kW + L.xidx[ix]) * kCH;
        wt[t]  = L.ywt[iy] * L.xwt[ix];
    }
    __syncthreads();
    const int lc = t & 31;
    const int pg = t >> 5;
    const _Float16* base = zt + (size_t)b * kPIX * kCH + (size_t)(cg + lc) * 8;
    float a[8] = {0.f, 0.f, 0.f, 0.f, 0.f, 0.f, 0.f, 0.f};
    for (int p = pg; p < np; p += 8) {
        const float w = wt[p];
        const half8 v = *(const half8*)(base + off[p]);
#pragma unroll
        for (int q = 0; q < 8; ++q) a[q] += w * (float)v[q];
    }
#pragma unroll
    for (int q = 0; q < 8; ++q) accs[pg][lc][q] = a[q];
    __syncthreads();
    // reduce: thread t -> chunk rc = t>>3, channel ch = t&7 (contiguous store)
    const int rc = t >> 3, ch = t & 7;
    float s = 0.f;
#pragma unroll
    for (int g = 0; g < 8; ++g) s += accs[g][rc][ch];
    x[(size_t)r * kCH + (size_t)(cg + rc) * 8 + ch] = (_Float16)(s * L.invCount);
}

// Fallback: gather directly from fp32 z (b,c,H,W) -> f16 x
__global__ __launch_bounds__(256) void roi_gather_direct(const float* __restrict__ z,
                                                         const float* __restrict__ bboxes,
                                                         _Float16* __restrict__ x) {
    const int r = blockIdx.x;
    const int b = r >> 7;
    __shared__ RoiLists L;
    if (threadIdx.x == 0) build_lists(bboxes, r, &L);
    __syncthreads();
    const int ny = L.ny, nx = L.nx;
    const float ic = L.invCount;
    const float* zb = z + (size_t)b * kCH * kPIX;
    for (int c = threadIdx.x; c < kCH; c += 256) {
        const float* zc = zb + (size_t)c * kPIX;
        float acc = 0.f;
        for (int iy = 0; iy < ny; ++iy) {
            const float wy = L.ywt[iy];
            const int base = L.yidx[iy] * kW;
            for (int ix = 0; ix < nx; ++ix)
                acc += wy * L.xwt[ix] * zc[base + L.xidx[ix]];
        }
        x[(size_t)r * kCH + c] = (_Float16)(acc * ic);
    }
}

// ---------------------------------------------------------------------------
// ALL weight transposes+converts in ONE launch.
// W1 (1280x5120): 6400 tiles; W2 (5120x1024): 5120; O (2048x1024): 2048;
// S3 (256x1024): 256. Total 13824 blocks of (32,8).
// ---------------------------------------------------------------------------
__global__ __launch_bounds__(256) void convert_all(const float* __restrict__ W1,
                                                   const float* __restrict__ W2,
                                                   const float* __restrict__ O,
                                                   const float* __restrict__ S3,
                                                   _Float16* __restrict__ W1t,
                                                   _Float16* __restrict__ W2t,
                                                   _Float16* __restrict__ Ot,
                                                   _Float16* __restrict__ S3t) {
    const int bid = blockIdx.x;
    const float* W; _Float16* Wt; int K, N, tile;
    if (bid < 6400)        { W = W1; Wt = W1t; K = kCH;    N = kINNER; tile = bid; }
    else if (bid < 11520)  { W = W2; Wt = W2t; K = kINNER; N = kOUTC;  tile = bid - 6400; }
    else if (bid < 13568)  { W = O;  Wt = Ot;  K = kXE;    N = kOUTC;  tile = bid - 11520; }
    else                   { W = S3; Wt = S3t; K = kE2;    N = kOUTC;  tile = bid - 13568; }
    const int nt = N / 32;
    const int n0 = (tile % nt) * 32;
    const int k0 = (tile / nt) * 32;
    __shared__ float tilebuf[32][33];  // [k][n]
    const int tx = threadIdx.x;     // 0..31
    const int ty = threadIdx.y;     // 0..7
#pragma unroll
    for (int i = 0; i < 4; ++i)
        tilebuf[ty + i * 8][tx] = W[(size_t)(k0 + ty + i * 8) * N + n0 + tx];
    __syncthreads();
#pragma unroll
    for (int i = 0; i < 4; ++i)
        Wt[(size_t)(n0 + ty + i * 8) * K + k0 + tx] = (_Float16)tilebuf[tx][ty + i * 8];
}

// ---------------------------------------------------------------------------
// f16 MFMA GEMM (NT), 128x128 tile, BK=32, 256 threads = 4 waves.
// Double-buffered global_load_lds staging (proven in round 3).
//   FUSED=true : single pass over Kfull; epilogue adds bias (+ReLU), stores at ldc.
//   FUSED=false: split-K partial (blockIdx.z), raw fp32 plane store -> P.
// ---------------------------------------------------------------------------
template <int NSPLIT, bool FUSED, bool RELU, bool F16OUT>
__global__ __launch_bounds__(256) void gemm_f16(const _Float16* __restrict__ A,
                                                const _Float16* __restrict__ Bt,
                                                const float* __restrict__ bias,
                                                void* __restrict__ Out,
                                                int Kfull, int ldc) {
    __shared__ _Float16 As[2][128 * 32];   // [buf][m][k] row-major, chunk c at [c*8]
    __shared__ _Float16 Bs[2][128 * 32];   // [buf][n][k] row-major
    const int t    = threadIdx.x;
    const int lane = t & 63;
    const int wave = t >> 6;
    const int m0 = blockIdx.y * 128, n0 = blockIdx.x * 128;
    const int Ksplit = Kfull / NSPLIT;
    const int s  = FUSED ? 0 : blockIdx.z;
    const int Nn = gridDim.x * 128;
    const int Mm = gridDim.y * 128;

    const int c0 = t, c1 = t + 256;
    const _Float16* Ag0 = A + (size_t)(m0 + (c0 >> 2)) * Kfull + (c0 & 3) * 8 + s * Ksplit;
    const _Float16* Ag1 = A + (size_t)(m0 + (c1 >> 2)) * Kfull + (c1 & 3) * 8 + s * Ksplit;
    const _Float16* Bg0 = Bt + (size_t)(n0 + (c0 >> 2)) * Kfull + (c0 & 3) * 8 + s * Ksplit;
    const _Float16* Bg1 = Bt + (size_t)(n0 + (c1 >> 2)) * Kfull + (c1 & 3) * 8 + s * Ksplit;

    const int wm = (wave >> 1) * 64;       // wave row offset in tile
    const int wn = (wave & 1) * 64;        // wave col offset in tile
    const int fm = lane & 15;              // fragment row/col within 16
    const int kq = (lane >> 4) * 8;        // fragment k offset

    floatx4 acc[4][4];
#pragma unroll
    for (int i = 0; i < 4; ++i)
#pragma unroll
        for (int j = 0; j < 4; ++j) acc[i][j] = (floatx4){0.f, 0.f, 0.f, 0.f};

    const int nsteps = Ksplit / 32;

    // prologue: stage tile 0 into buf 0
    gload_lds16(Ag0, &As[0][c0 * 8]);
    gload_lds16(Ag1, &As[0][c1 * 8]);
    gload_lds16(Bg0, &Bs[0][c0 * 8]);
    gload_lds16(Bg1, &Bs[0][c1 * 8]);
    __syncthreads();

    for (int ks = 0; ks < nsteps; ++ks) {
        const int cur = ks & 1;
        if (ks + 1 < nsteps) {           // stage next tile into the other buf
            const int kn = (ks + 1) * 32;
            gload_lds16(Ag0 + kn, &As[cur ^ 1][c0 * 8]);
            gload_lds16(Ag1 + kn, &As[cur ^ 1][c1 * 8]);
            gload_lds16(Bg0 + kn, &Bs[cur ^ 1][c0 * 8]);
            gload_lds16(Bg1 + kn, &Bs[cur ^ 1][c1 * 8]);
        }
        half8 af[4], bfv[4];
#pragma unroll
        for (int i = 0; i < 4; ++i)
            af[i] = *(const half8*)&As[cur][(wm + i * 16 + fm) * 32 + kq];
#pragma unroll
        for (int j = 0; j < 4; ++j)
            bfv[j] = *(const half8*)&Bs[cur][(wn + j * 16 + fm) * 32 + kq];
#pragma unroll
        for (int i = 0; i < 4; ++i)
#pragma unroll
            for (int j = 0; j < 4; ++j)
                acc[i][j] = __builtin_amdgcn_mfma_f32_16x16x32_f16(af[i], bfv[j], acc[i][j], 0, 0, 0);
        __syncthreads();                 // drains next-stage vmcnt (mostly covered)
    }

    // Epilogue. C/D layout: col = lane&15, row = (lane>>4)*4 + rr
    const int qr = (lane >> 4) * 4;
    if (FUSED) {
#pragma unroll
        for (int j = 0; j < 4; ++j) {
            const int col = n0 + wn + j * 16 + fm;
            const float bv = bias[col];
#pragma unroll
            for (int i = 0; i < 4; ++i) {
                const int row = m0 + wm + i * 16 + qr;
#pragma unroll
                for (int rr = 0; rr < 4; ++rr) {
                    float v = acc[i][j][rr] + bv;
                    if (RELU) v = fmaxf(v, 0.f);
                    if (F16OUT)
                        ((_Float16*)Out)[(size_t)(row + rr) * ldc + col] = (_Float16)v;
                    else
                        ((float*)Out)[(size_t)(row + rr) * ldc + col] = v;
                }
            }
        }
    } else {
        float* Pp = (float*)Out + (size_t)s * Mm * Nn;
#pragma unroll
        for (int j = 0; j < 4; ++j) {
            const int col = n0 + wn + j * 16 + fm;
#pragma unroll
            for (int i = 0; i < 4; ++i) {
                const int row = m0 + wm + i * 16 + qr;
#pragma unroll
                for (int rr = 0; rr < 4; ++rr)
                    Pp[(size_t)(row + rr) * Nn + col] = acc[i][j][rr];
            }
        }
    }
}

// ---------------------------------------------------------------------------
// Split-K reduce + bias + (relu) + convert.
// ---------------------------------------------------------------------------
template <bool RELU, bool F16OUT, int NSPLIT>
__global__ __launch_bounds__(256) void reduce_splitk(const float* __restrict__ P,
                                                     const float* __restrict__ bias,
                                                     void* __restrict__ Cout,
                                                     int Nn, int ldc) {
    const size_t idx = ((size_t)blockIdx.x * 256 + threadIdx.x) * 4;
    const size_t MN  = (size_t)gridDim.x * 1024;
    const int m = (int)(idx / (size_t)Nn);
    const int n = (int)(idx % (size_t)Nn);
    float4 acc = *(const float4*)(P + idx);
#pragma unroll
    for (int s = 1; s < NSPLIT; ++s) {
        const float4 v = *(const float4*)(P + (size_t)s * MN + idx);
        acc.x += v.x; acc.y += v.y; acc.z += v.z; acc.w += v.w;
    }
    const float4 b4 = *(const float4*)(bias + n);
    acc.x += b4.x; acc.y += b4.y; acc.z += b4.z; acc.w += b4.w;
    if (RELU) {
        acc.x = fmaxf(acc.x, 0.f); acc.y = fmaxf(acc.y, 0.f);
        acc.z = fmaxf(acc.z, 0.f); acc.w = fmaxf(acc.w, 0.f);
    }
    if (F16OUT) {
        union { _Float16 h[4]; uint2 u; } pk;
        pk.h[0] = (_Float16)acc.x; pk.h[1] = (_Float16)acc.y;
        pk.h[2] = (_Float16)acc.z; pk.h[3] = (_Float16)acc.w;
        *(uint2*)((_Float16*)Cout + (size_t)m * ldc + n) = pk.u;
    } else {
        *(float4*)((float*)Cout + (size_t)m * ldc + n) = acc;
    }
}

// ---------------------------------------------------------------------------
// Size-embedding MLP layers 1+2: 2 -> 64 -> 256, f16 out (kR x 256).
// ---------------------------------------------------------------------------
__global__ __launch_bounds__(256) void size_mlp12(const float* __restrict__ bboxes,
                                                  const float* __restrict__ S1,
                                                  const float* __restrict__ sb1,
                                                  const float* __restrict__ S2,
                                                  const float* __restrict__ sb2,
                                                  _Float16* __restrict__ h2out) {
    const int r0 = blockIdx.x * 4;
    const int t  = threadIdx.x;
    __shared__ float sz[4][2];     // [row][{h,w}]
    __shared__ float h1[4][64];
    if (t < 8) {
        const int row = t >> 1;
        const int c   = t & 1;
        const float* bb = bboxes + (size_t)(r0 + row) * 4;
        sz[row][c] = (c == 0) ? (bb[3] - bb[1]) : (bb[2] - bb[0]);
    }
    __syncthreads();
    {   // layer 1: 4 rows x 64 = 256 items, one per thread
        const int row = t >> 6;
        const int j   = t & 63;
        const float v = sz[row][0] * S1[j] + sz[row][1] * S1[64 + j] + sb1[j];
        h1[row][j] = fmaxf(v, 0.0f);
    }
    __syncthreads();
    {   // layer 2: j = t, 4 rows register-blocked
        float acc[4];
        const float b = sb2[t];
#pragma unroll
        for (int row = 0; row < 4; ++row) acc[row] = b;
#pragma unroll 16
        for (int k = 0; k < 64; ++k) {
            const float w = S2[k * 256 + t];
#pragma unroll
            for (int row = 0; row < 4; ++row) acc[row] += h1[row][k] * w;
        }
#pragma unroll
        for (int row = 0; row < 4; ++row)
            h2out[(size_t)(r0 + row) * kE2 + t] = (_Float16)fmaxf(acc[row], 0.0f);
    }
}

// ---------------------------------------------------------------------------
extern "C" void kernel_launch(void* const* d_in, const int* in_sizes, int n_in,
                              void* d_out, int out_size, void* d_ws, size_t ws_size,
                              hipStream_t stream) {
    (void)in_sizes; (void)n_in; (void)out_size;
    const float* z   = (const float*)d_in[0];
    const float* bb  = (const float*)d_in[1];
    const float* W1  = (const float*)d_in[2];
    const float* b1  = (const float*)d_in[3];
    const float* W2  = (const float*)d_in[4];
    const float* b2  = (const float*)d_in[5];
    const float* S1  = (const float*)d_in[6];
    const float* sb1 = (const float*)d_in[7];
    const float* S2  = (const float*)d_in[8];
    const float* sb2 = (const float*)d_in[9];
    const float* S3  = (const float*)d_in[10];
    const float* sb3 = (const float*)d_in[11];
    const float* O   = (const float*)d_in[12];
    const float* ob  = (const float*)d_in[13];
    float* out = (float*)d_out;

    char* ws = (char*)d_ws;
    size_t off = 0;
    auto alloc = [&](size_t bytes) {
        void* p = ws + off;
        off += (bytes + 255) & ~(size_t)255;
        return p;
    };
    _Float16* x    = (_Float16*)alloc((size_t)kR * kCH * 2);        //  2.6 MB
    _Float16* h    = (_Float16*)alloc((size_t)kR * kINNER * 2);     // 10.5 MB
    _Float16* xe   = (_Float16*)alloc((size_t)kR * kXE * 2);        //  4.2 MB
    _Float16* W1t  = (_Float16*)alloc((size_t)kINNER * kCH * 2);    // 13.1 MB
    _Float16* W2t  = (_Float16*)alloc((size_t)kOUTC * kINNER * 2);  // 10.5 MB
    _Float16* Ot   = (_Float16*)alloc((size_t)kOUTC * kXE * 2);     //  4.2 MB
    _Float16* S3t  = (_Float16*)alloc((size_t)kOUTC * kE2 * 2);     //  0.5 MB
    _Float16* h2f  = (_Float16*)alloc((size_t)kR * kE2 * 2);        //  0.5 MB
    float*    P    = (float*)alloc((size_t)8 * kR * kOUTC * 4);     // 33.6 MB (split-8 partials)
    const size_t ztBytes = (size_t)kBS * kPIX * kCH * 2;            // 83.9 MB
    _Float16* zt  = (_Float16*)(ws + off);
    const bool useT = (off + ztBytes) <= ws_size;

    // 0) all weight conversions in one launch
    hipLaunchKernelGGL(convert_all, dim3(13824), dim3(32, 8), 0, stream,
                       W1, W2, O, S3, W1t, W2t, Ot, S3t);

    // 1) ROI-align features -> x (1024 x 1280 f16)
    if (useT) {
        hipLaunchKernelGGL(transpose_z_f16, dim3(kPIX / 32, kCH / 64, kBS), dim3(32, 8), 0,
                           stream, z, zt);
        hipLaunchKernelGGL(roi_gather_f16_v2, dim3(kCH / 256, kR), dim3(256), 0, stream,
                           zt, bb, x);
    } else {
        hipLaunchKernelGGL(roi_gather_direct, dim3(kR), dim3(256), 0, stream, z, bb, x);
    }

    // 2) size-embedding MLP layers 1+2 -> h2f (1024 x 256 f16)
    hipLaunchKernelGGL(size_mlp12, dim3(kR / 4), dim3(256), 0, stream,
                       bb, S1, sb1, S2, sb2, h2f);
    // 2b) layer 3 on MFMA, fused 128x128 (64 blocks, 8 k-steps):
    //     xe[:, 1024:2048] = h2f @ S3 + sb3
    hipLaunchKernelGGL((gemm_f16<1, true, false, true>),
                       dim3(kOUTC / 128, kR / 128), dim3(256), 0, stream,
                       h2f, S3t, sb3, xe + kOUTC, kE2, kXE);

    // 3) h = relu(x @ W1 + b1): fused 128x128, 320 blocks, 40 k-steps
    hipLaunchKernelGGL((gemm_f16<1, true, true, true>),
                       dim3(kINNER / 128, kR / 128), dim3(256), 0, stream,
                       x, W1t, b1, h, kCH, kINNER);

    // 4) xe[:, 0:1024] = h @ W2 + b2: split-K x8 (512 blocks = 2/CU, 20 k-steps)
    hipLaunchKernelGGL((gemm_f16<8, false, false, false>),
                       dim3(kOUTC / 128, kR / 128, 8), dim3(256), 0, stream,
                       h, W2t, nullptr, P, kINNER, 0);
    hipLaunchKernelGGL((reduce_splitk<false, true, 8>),
                       dim3((size_t)kR * kOUTC / 1024), dim3(256), 0, stream,
                       P, b2, xe, kOUTC, kXE);

    // 5) out = xe @ O + ob: split-K x8 (512 blocks = 2/CU, 8 k-steps)
    hipLaunchKernelGGL((gemm_f16<8, false, false, false>),
                       dim3(kOUTC / 128, kR / 128, 8), dim3(256), 0, stream,
                       xe, Ot, nullptr, P, kXE, 0);
    hipLaunchKernelGGL((reduce_splitk<false, false, 8>),
                       dim3((size_t)kR * kOUTC / 1024), dim3(256), 0, stream,
                       P, ob, out, kOUTC, kOUTC);
}

// Round 6
// 424.048 us; speedup vs baseline: 1.1657x; 1.0377x over previous
//
#include <hip/hip_runtime.h>

// Problem constants
static constexpr int kBS    = 8;
static constexpr int kNROI  = 128;
static constexpr int kR     = kBS * kNROI;   // 1024 rows
static constexpr int kCH    = 1280;
static constexpr int kH     = 64;
static constexpr int kW     = 64;
static constexpr int kPIX   = kH * kW;       // 4096
static constexpr int kINNER = 5120;
static constexpr int kOUTC  = 1024;
static constexpr int kXE    = 2 * kOUTC;     // 2048 concat width
static constexpr int kE2    = 256;           // size-MLP hidden 2

typedef _Float16 half8 __attribute__((ext_vector_type(8)));   // f16x8 MFMA A/B frag
typedef float floatx4 __attribute__((ext_vector_type(4)));    // MFMA C/D frag

// Async global->LDS 16B copy. LDS dest must be wave-uniform base + lane*16,
// which our chunk-index==threadIdx staging layout satisfies exactly.
__device__ __forceinline__ void gload_lds16(const _Float16* g, _Float16* l) {
    __builtin_amdgcn_global_load_lds(
        (const __attribute__((address_space(1))) void*)g,
        (__attribute__((address_space(3))) void*)l,
        16, 0, 0);
}

// ---------------------------------------------------------------------------
// PREP mega-kernel: all independent prep work in ONE launch (saves 2 dispatches).
// Block ranges (threads (32,8)):
//   [0, 13824)          : weight transpose+convert tiles (W1, W2, O, S3)
//   [13824, 14080)      : size-MLP layers 1+2 (4 ROIs per block)
//   [14080, 14080+20480): z transpose+convert (b, c, HW) fp32 -> (b, HW, c) f16
// If zt doesn't fit the workspace, launch with grid = 14080 (no transpose).
// ---------------------------------------------------------------------------
static constexpr int kPrepConvEnd = 13824;
static constexpr int kPrepMlpEnd  = 14080;
static constexpr int kPrepAllEnd  = 14080 + (kPIX / 32) * (kCH / 64) * kBS;  // 34560

__global__ __launch_bounds__(256) void prep_all(const float* __restrict__ z,
                                                _Float16* __restrict__ zt,
                                                const float* __restrict__ W1,
                                                const float* __restrict__ W2,
                                                const float* __restrict__ O,
                                                const float* __restrict__ S3,
                                                _Float16* __restrict__ W1t,
                                                _Float16* __restrict__ W2t,
                                                _Float16* __restrict__ Ot,
                                                _Float16* __restrict__ S3t,
                                                const float* __restrict__ bboxes,
                                                const float* __restrict__ S1,
                                                const float* __restrict__ sb1,
                                                const float* __restrict__ S2,
                                                const float* __restrict__ sb2,
                                                _Float16* __restrict__ h2f) {
    __shared__ float smem[64 * 33];   // 8.25 KB, reused by all branches
    const int bid = blockIdx.x;
    const int tx = threadIdx.x;       // 0..31
    const int ty = threadIdx.y;       // 0..7

    if (bid < kPrepConvEnd) {
        // ---- weight convert+transpose: W (K x N) fp32 -> Wt (N x K) f16 ----
        const float* W; _Float16* Wt; int K, N, tile;
        if (bid < 6400)        { W = W1; Wt = W1t; K = kCH;    N = kINNER; tile = bid; }
        else if (bid < 11520)  { W = W2; Wt = W2t; K = kINNER; N = kOUTC;  tile = bid - 6400; }
        else if (bid < 13568)  { W = O;  Wt = Ot;  K = kXE;    N = kOUTC;  tile = bid - 11520; }
        else                   { W = S3; Wt = S3t; K = kE2;    N = kOUTC;  tile = bid - 13568; }
        const int nt = N / 32;
        const int n0 = (tile % nt) * 32;
        const int k0 = (tile / nt) * 32;
        float* tileb = smem;          // [32][33]
#pragma unroll
        for (int i = 0; i < 4; ++i)
            tileb[(ty + i * 8) * 33 + tx] = W[(size_t)(k0 + ty + i * 8) * N + n0 + tx];
        __syncthreads();
#pragma unroll
        for (int i = 0; i < 4; ++i)
            Wt[(size_t)(n0 + ty + i * 8) * K + k0 + tx] = (_Float16)tileb[tx * 33 + ty + i * 8];
    } else if (bid < kPrepMlpEnd) {
        // ---- size-MLP layers 1+2: 2 -> 64 -> 256, 4 rows/block ----
        const int r0 = (bid - kPrepConvEnd) * 4;
        const int t  = ty * 32 + tx;  // 0..255
        float* sz = smem;             // [4][2]
        float* h1 = smem + 8;         // [4][64]
        if (t < 8) {
            const int row = t >> 1;
            const int c   = t & 1;
            const float* bb = bboxes + (size_t)(r0 + row) * 4;
            sz[row * 2 + c] = (c == 0) ? (bb[3] - bb[1]) : (bb[2] - bb[0]);
        }
        __syncthreads();
        {   // layer 1: 4 rows x 64 = 256 items, one per thread
            const int row = t >> 6;
            const int j   = t & 63;
            const float v = sz[row * 2] * S1[j] + sz[row * 2 + 1] * S1[64 + j] + sb1[j];
            h1[row * 64 + j] = fmaxf(v, 0.0f);
        }
        __syncthreads();
        {   // layer 2: j = t, 4 rows register-blocked
            float acc[4];
            const float b = sb2[t];
#pragma unroll
            for (int row = 0; row < 4; ++row) acc[row] = b;
#pragma unroll 16
            for (int k = 0; k < 64; ++k) {
                const float w = S2[k * 256 + t];
#pragma unroll
                for (int row = 0; row < 4; ++row) acc[row] += h1[row * 64 + k] * w;
            }
#pragma unroll
            for (int row = 0; row < 4; ++row)
                h2f[(size_t)(r0 + row) * kE2 + t] = (_Float16)fmaxf(acc[row], 0.0f);
        }
    } else {
        // ---- z transpose+convert (verified round-3 body) ----
        const int tb = bid - kPrepMlpEnd;
        const int perB = (kPIX / 32) * (kCH / 64);   // 2560
        const int b   = tb / perB;
        const int rem = tb - b * perB;
        const int p0 = (rem % (kPIX / 32)) * 32;
        const int c0 = (rem / (kPIX / 32)) * 64;
        float* tile = smem;           // [64][33]
        const float* zb = z + (size_t)b * kCH * kPIX;
        _Float16* ztb = zt + (size_t)b * kPIX * kCH;
#pragma unroll
        for (int i = 0; i < 8; ++i) {
            const int cl = ty + i * 8;   // 0..63
            tile[cl * 33 + tx] = zb[(size_t)(c0 + cl) * kPIX + p0 + tx];
        }
        __syncthreads();
#pragma unroll
        for (int i = 0; i < 4; ++i) {
            const int pl = ty + i * 8;   // 0..31
            union { _Float16 hh[2]; unsigned int u; } pk;
            pk.hh[0] = (_Float16)tile[(2 * tx) * 33 + pl];
            pk.hh[1] = (_Float16)tile[(2 * tx + 1) * 33 + pl];
            *(unsigned int*)(ztb + (size_t)(p0 + pl) * kCH + c0 + 2 * tx) = pk.u;
        }
    }
}

// ---------------------------------------------------------------------------
// Consolidated ROI weights: distinct pixel rows/cols with summed separable
// weights. Sample spacing <= 1 px, so distinct indices form a contiguous
// window of <= 10; bilinear weights sum linearly per distinct row/col:
//   sum_g wy_g*wx_g*v[y_g][x_g] = (sum wy per row) * (sum wx per col) * v.
// Cuts gather points from 4*gh*gw (avg ~81) to (<=gh+2)(<=gw+2) (avg ~30).
// ---------------------------------------------------------------------------
struct RoiW {
    int   ymin, xmin, nyd, nxd;
    float ywt[12], xwt[12];
    float invCount;
};

__device__ inline void build_wcons(const float* __restrict__ bboxes, int r, RoiW* L) {
    const float x1 = bboxes[r * 4 + 0] * 0.125f - 0.5f;
    const float y1 = bboxes[r * 4 + 1] * 0.125f - 0.5f;
    const float x2 = bboxes[r * 4 + 2] * 0.125f - 0.5f;
    const float y2 = bboxes[r * 4 + 3] * 0.125f - 0.5f;
    const float rw = x2 - x1, rh = y2 - y1;
    const float gwf = fminf(fmaxf(ceilf(rw), 1.0f), 8.0f);
    const float ghf = fminf(fmaxf(ceilf(rh), 1.0f), 8.0f);
    const int gw = (int)gwf, gh = (int)ghf;
    L->invCount = 1.0f / (gwf * ghf);

#pragma unroll
    for (int i = 0; i < 12; ++i) { L->ywt[i] = 0.0f; L->xwt[i] = 0.0f; }

    int ymin = 0, last = 0;
    for (int g = 0; g < gh; ++g) {
        const float c   = y1 + ((float)g + 0.5f) * rh / ghf;
        const bool oob  = (c < -1.0f) || (c > 64.0f);
        const float cc  = fmaxf(c, 0.0f);
        const float lo0 = floorf(cc);
        const bool hic  = (lo0 >= 63.0f);
        const int lo    = (int)fminf(lo0, 63.0f);
        const int hi    = (int)fminf(lo0 + 1.0f, 63.0f);
        const float fr  = hic ? 0.0f : (cc - lo0);
        const float m   = oob ? 0.0f : 1.0f;
        if (g == 0) ymin = lo;
        const int il = min(lo - ymin, 11);
        const int ih = min(hi - ymin, 11);
        L->ywt[il] += m * (1.0f - fr);
        L->ywt[ih] += m * fr;
        last = hi;
    }
    L->ymin = ymin;
    L->nyd  = min(last - ymin + 1, 12);

    int xmin = 0; last = 0;
    for (int g = 0; g < gw; ++g) {
        const float c   = x1 + ((float)g + 0.5f) * rw / gwf;
        const bool oob  = (c < -1.0f) || (c > 64.0f);
        const float cc  = fmaxf(c, 0.0f);
        const float lo0 = floorf(cc);
        const bool hic  = (lo0 >= 63.0f);
        const int lo    = (int)fminf(lo0, 63.0f);
        const int hi    = (int)fminf(lo0 + 1.0f, 63.0f);
        const float fr  = hic ? 0.0f : (cc - lo0);
        const float m   = oob ? 0.0f : 1.0f;
        if (g == 0) xmin = lo;
        const int il = min(lo - xmin, 11);
        const int ih = min(hi - xmin, 11);
        L->xwt[il] += m * (1.0f - fr);
        L->xwt[ih] += m * fr;
        last = hi;
    }
    L->xmin = xmin;
    L->nxd  = min(last - xmin + 1, 12);
}

// ---------------------------------------------------------------------------
// ROI gather v3 from channels-last f16 zt -> f16 x (1024 x 1280).
// Grid (5, kR): blockIdx.x = 32-chunk channel group, blockIdx.y = ROI.
// Consolidated point list (<= 144, avg ~30). 8-way point split per chunk,
// LDS tree-reduce, coalesced output.
// ---------------------------------------------------------------------------
__global__ __launch_bounds__(256) void roi_gather_f16_v3(const _Float16* __restrict__ zt,
                                                         const float* __restrict__ bboxes,
                                                         _Float16* __restrict__ x) {
    const int r  = blockIdx.y;
    const int b  = r >> 7;
    const int cg = blockIdx.x * 32;    // base chunk (c8 units) of this block
    const int t  = threadIdx.x;
    __shared__ RoiW L;
    __shared__ int   off[144];
    __shared__ float wt[144];
    __shared__ float accs[8][32][9];   // [pg][chunk][ch] (+1 pad col)
    if (t == 0) build_wcons(bboxes, r, &L);
    __syncthreads();
    const int np = L.nyd * L.nxd;      // <= 144
    if (t < np) {
        const int iy = t / L.nxd;
        const int ix = t - iy * L.nxd;
        off[t] = ((L.ymin + iy) * kW + (L.xmin + ix)) * kCH;
        wt[t]  = L.ywt[iy] * L.xwt[ix];
    }
    __syncthreads();
    const int lc = t & 31;
    const int pg = t >> 5;
    const _Float16* base = zt + (size_t)b * kPIX * kCH + (size_t)(cg + lc) * 8;
    float a[8] = {0.f, 0.f, 0.f, 0.f, 0.f, 0.f, 0.f, 0.f};
    for (int p = pg; p < np; p += 8) {
        const float w = wt[p];
        const half8 v = *(const half8*)(base + off[p]);
#pragma unroll
        for (int q = 0; q < 8; ++q) a[q] += w * (float)v[q];
    }
#pragma unroll
    for (int q = 0; q < 8; ++q) accs[pg][lc][q] = a[q];
    __syncthreads();
    // reduce: thread t -> chunk rc = t>>3, channel ch = t&7 (contiguous store)
    const int rc = t >> 3, ch = t & 7;
    float s = 0.f;
#pragma unroll
    for (int g = 0; g < 8; ++g) s += accs[g][rc][ch];
    x[(size_t)r * kCH + (size_t)(cg + rc) * 8 + ch] = (_Float16)(s * L.invCount);
}

// Fallback: gather directly from fp32 z (b,c,H,W) -> f16 x (consolidated too)
__global__ __launch_bounds__(256) void roi_gather_direct(const float* __restrict__ z,
                                                         const float* __restrict__ bboxes,
                                                         _Float16* __restrict__ x) {
    const int r = blockIdx.x;
    const int b = r >> 7;
    __shared__ RoiW L;
    if (threadIdx.x == 0) build_wcons(bboxes, r, &L);
    __syncthreads();
    const float ic = L.invCount;
    const float* zb = z + (size_t)b * kCH * kPIX;
    for (int c = threadIdx.x; c < kCH; c += 256) {
        const float* zc = zb + (size_t)c * kPIX;
        float acc = 0.f;
        for (int iy = 0; iy < L.nyd; ++iy) {
            const float wy = L.ywt[iy];
            const int base = (L.ymin + iy) * kW + L.xmin;
            for (int ix = 0; ix < L.nxd; ++ix)
                acc += wy * L.xwt[ix] * zc[base + ix];
        }
        x[(size_t)r * kCH + c] = (_Float16)(acc * ic);
    }
}

// ---------------------------------------------------------------------------
// f16 MFMA GEMM (NT), 128x128 tile, BK=32, 256 threads = 4 waves.
// Double-buffered global_load_lds staging (verified round 3/5).
// Split-K partial (blockIdx.z), raw fp32 plane store -> P.
// ---------------------------------------------------------------------------
template <int NSPLIT>
__global__ __launch_bounds__(256) void gemm_f16_sk(const _Float16* __restrict__ A,
                                                   const _Float16* __restrict__ Bt,
                                                   float* __restrict__ P,
                                                   int Kfull) {
    __shared__ _Float16 As[2][128 * 32];
    __shared__ _Float16 Bs[2][128 * 32];
    const int t    = threadIdx.x;
    const int lane = t & 63;
    const int wave = t >> 6;
    const int m0 = blockIdx.y * 128, n0 = blockIdx.x * 128;
    const int Ksplit = Kfull / NSPLIT;
    const int s  = blockIdx.z;
    const int Nn = gridDim.x * 128;
    const int Mm = gridDim.y * 128;

    const int c0 = t, c1 = t + 256;
    const _Float16* Ag0 = A + (size_t)(m0 + (c0 >> 2)) * Kfull + (c0 & 3) * 8 + s * Ksplit;
    const _Float16* Ag1 = A + (size_t)(m0 + (c1 >> 2)) * Kfull + (c1 & 3) * 8 + s * Ksplit;
    const _Float16* Bg0 = Bt + (size_t)(n0 + (c0 >> 2)) * Kfull + (c0 & 3) * 8 + s * Ksplit;
    const _Float16* Bg1 = Bt + (size_t)(n0 + (c1 >> 2)) * Kfull + (c1 & 3) * 8 + s * Ksplit;

    const int wm = (wave >> 1) * 64;
    const int wn = (wave & 1) * 64;
    const int fm = lane & 15;
    const int kq = (lane >> 4) * 8;

    floatx4 acc[4][4];
#pragma unroll
    for (int i = 0; i < 4; ++i)
#pragma unroll
        for (int j = 0; j < 4; ++j) acc[i][j] = (floatx4){0.f, 0.f, 0.f, 0.f};

    const int nsteps = Ksplit / 32;
    gload_lds16(Ag0, &As[0][c0 * 8]);
    gload_lds16(Ag1, &As[0][c1 * 8]);
    gload_lds16(Bg0, &Bs[0][c0 * 8]);
    gload_lds16(Bg1, &Bs[0][c1 * 8]);
    __syncthreads();

    for (int ks = 0; ks < nsteps; ++ks) {
        const int cur = ks & 1;
        if (ks + 1 < nsteps) {
            const int kn = (ks + 1) * 32;
            gload_lds16(Ag0 + kn, &As[cur ^ 1][c0 * 8]);
            gload_lds16(Ag1 + kn, &As[cur ^ 1][c1 * 8]);
            gload_lds16(Bg0 + kn, &Bs[cur ^ 1][c0 * 8]);
            gload_lds16(Bg1 + kn, &Bs[cur ^ 1][c1 * 8]);
        }
        half8 af[4], bfv[4];
#pragma unroll
        for (int i = 0; i < 4; ++i)
            af[i] = *(const half8*)&As[cur][(wm + i * 16 + fm) * 32 + kq];
#pragma unroll
        for (int j = 0; j < 4; ++j)
            bfv[j] = *(const half8*)&Bs[cur][(wn + j * 16 + fm) * 32 + kq];
#pragma unroll
        for (int i = 0; i < 4; ++i)
#pragma unroll
            for (int j = 0; j < 4; ++j)
                acc[i][j] = __builtin_amdgcn_mfma_f32_16x16x32_f16(af[i], bfv[j], acc[i][j], 0, 0, 0);
        __syncthreads();
    }

    float* Pp = P + (size_t)s * Mm * Nn;
    const int qr = (lane >> 4) * 4;
#pragma unroll
    for (int j = 0; j < 4; ++j) {
        const int col = n0 + wn + j * 16 + fm;
#pragma unroll
        for (int i = 0; i < 4; ++i) {
            const int row = m0 + wm + i * 16 + qr;
#pragma unroll
            for (int rr = 0; rr < 4; ++rr)
                Pp[(size_t)(row + rr) * Nn + col] = acc[i][j][rr];
        }
    }
}

// ---------------------------------------------------------------------------
// DUAL fused GEMM: one launch runs both the S3-embedding GEMM (64 blocks)
// and GEMM1 (320 blocks) -- packs the GPU and saves a dispatch. Same verified
// dbuf body as round 5, runtime job decode, runtime relu (uniform branch).
//   job0 (bid < 64):  xe[:,1024:2048] = h2f @ S3t^T + sb3        (K=256)
//   job1 (bid >= 64): h = relu(x @ W1t^T + b1)                   (K=1280)
// ---------------------------------------------------------------------------
__global__ __launch_bounds__(256) void gemm_dual(const _Float16* __restrict__ h2f,
                                                 const _Float16* __restrict__ S3t,
                                                 const float* __restrict__ sb3,
                                                 _Float16* __restrict__ xeR,
                                                 const _Float16* __restrict__ x,
                                                 const _Float16* __restrict__ W1t,
                                                 const float* __restrict__ b1,
                                                 _Float16* __restrict__ h) {
    __shared__ _Float16 As[2][128 * 32];
    __shared__ _Float16 Bs[2][128 * 32];
    const int bid = blockIdx.x;
    const _Float16* A; const _Float16* Bt; const float* bias; _Float16* Out;
    int Kfull, ldc, nbn, tile; bool relu;
    if (bid < 64) {
        A = h2f; Bt = S3t; bias = sb3; Out = xeR;
        Kfull = kE2; ldc = kXE; relu = false; nbn = kOUTC / 128; tile = bid;
    } else {
        A = x; Bt = W1t; bias = b1; Out = h;
        Kfull = kCH; ldc = kINNER; relu = true; nbn = kINNER / 128; tile = bid - 64;
    }
    const int n0 = (tile % nbn) * 128;
    const int m0 = (tile / nbn) * 128;

    const int t    = threadIdx.x;
    const int lane = t & 63;
    const int wave = t >> 6;

    const int c0 = t, c1 = t + 256;
    const _Float16* Ag0 = A + (size_t)(m0 + (c0 >> 2)) * Kfull + (c0 & 3) * 8;
    const _Float16* Ag1 = A + (size_t)(m0 + (c1 >> 2)) * Kfull + (c1 & 3) * 8;
    const _Float16* Bg0 = Bt + (size_t)(n0 + (c0 >> 2)) * Kfull + (c0 & 3) * 8;
    const _Float16* Bg1 = Bt + (size_t)(n0 + (c1 >> 2)) * Kfull + (c1 & 3) * 8;

    const int wm = (wave >> 1) * 64;
    const int wn = (wave & 1) * 64;
    const int fm = lane & 15;
    const int kq = (lane >> 4) * 8;

    floatx4 acc[4][4];
#pragma unroll
    for (int i = 0; i < 4; ++i)
#pragma unroll
        for (int j = 0; j < 4; ++j) acc[i][j] = (floatx4){0.f, 0.f, 0.f, 0.f};

    const int nsteps = Kfull / 32;
    gload_lds16(Ag0, &As[0][c0 * 8]);
    gload_lds16(Ag1, &As[0][c1 * 8]);
    gload_lds16(Bg0, &Bs[0][c0 * 8]);
    gload_lds16(Bg1, &Bs[0][c1 * 8]);
    __syncthreads();

    for (int ks = 0; ks < nsteps; ++ks) {
        const int cur = ks & 1;
        if (ks + 1 < nsteps) {
            const int kn = (ks + 1) * 32;
            gload_lds16(Ag0 + kn, &As[cur ^ 1][c0 * 8]);
            gload_lds16(Ag1 + kn, &As[cur ^ 1][c1 * 8]);
            gload_lds16(Bg0 + kn, &Bs[cur ^ 1][c0 * 8]);
            gload_lds16(Bg1 + kn, &Bs[cur ^ 1][c1 * 8]);
        }
        half8 af[4], bfv[4];
#pragma unroll
        for (int i = 0; i < 4; ++i)
            af[i] = *(const half8*)&As[cur][(wm + i * 16 + fm) * 32 + kq];
#pragma unroll
        for (int j = 0; j < 4; ++j)
            bfv[j] = *(const half8*)&Bs[cur][(wn + j * 16 + fm) * 32 + kq];
#pragma unroll
        for (int i = 0; i < 4; ++i)
#pragma unroll
            for (int j = 0; j < 4; ++j)
                acc[i][j] = __builtin_amdgcn_mfma_f32_16x16x32_f16(af[i], bfv[j], acc[i][j], 0, 0, 0);
        __syncthreads();
    }

    // Epilogue: bias (+relu) -> f16 at ldc. C/D: col = lane&15, row = (lane>>4)*4+rr
    const int qr = (lane >> 4) * 4;
#pragma unroll
    for (int j = 0; j < 4; ++j) {
        const int col = n0 + wn + j * 16 + fm;
        const float bv = bias[col];
#pragma unroll
        for (int i = 0; i < 4; ++i) {
            const int row = m0 + wm + i * 16 + qr;
#pragma unroll
            for (int rr = 0; rr < 4; ++rr) {
                float v = acc[i][j][rr] + bv;
                if (relu) v = fmaxf(v, 0.f);
                Out[(size_t)(row + rr) * ldc + col] = (_Float16)v;
            }
        }
    }
}

// ---------------------------------------------------------------------------
// Split-K reduce + bias + (relu) + convert.
// ---------------------------------------------------------------------------
template <bool RELU, bool F16OUT, int NSPLIT>
__global__ __launch_bounds__(256) void reduce_splitk(const float* __restrict__ P,
                                                     const float* __restrict__ bias,
                                                     void* __restrict__ Cout,
                                                     int Nn, int ldc) {
    const size_t idx = ((size_t)blockIdx.x * 256 + threadIdx.x) * 4;
    const size_t MN  = (size_t)gridDim.x * 1024;
    const int m = (int)(idx / (size_t)Nn);
    const int n = (int)(idx % (size_t)Nn);
    float4 acc = *(const float4*)(P + idx);
#pragma unroll
    for (int s = 1; s < NSPLIT; ++s) {
        const float4 v = *(const float4*)(P + (size_t)s * MN + idx);
        acc.x += v.x; acc.y += v.y; acc.z += v.z; acc.w += v.w;
    }
    const float4 b4 = *(const float4*)(bias + n);
    acc.x += b4.x; acc.y += b4.y; acc.z += b4.z; acc.w += b4.w;
    if (RELU) {
        acc.x = fmaxf(acc.x, 0.f); acc.y = fmaxf(acc.y, 0.f);
        acc.z = fmaxf(acc.z, 0.f); acc.w = fmaxf(acc.w, 0.f);
    }
    if (F16OUT) {
        union { _Float16 h[4]; uint2 u; } pk;
        pk.h[0] = (_Float16)acc.x; pk.h[1] = (_Float16)acc.y;
        pk.h[2] = (_Float16)acc.z; pk.h[3] = (_Float16)acc.w;
        *(uint2*)((_Float16*)Cout + (size_t)m * ldc + n) = pk.u;
    } else {
        *(float4*)((float*)Cout + (size_t)m * ldc + n) = acc;
    }
}

// ---------------------------------------------------------------------------
extern "C" void kernel_launch(void* const* d_in, const int* in_sizes, int n_in,
                              void* d_out, int out_size, void* d_ws, size_t ws_size,
                              hipStream_t stream) {
    (void)in_sizes; (void)n_in; (void)out_size;
    const float* z   = (const float*)d_in[0];
    const float* bb  = (const float*)d_in[1];
    const float* W1  = (const float*)d_in[2];
    const float* b1  = (const float*)d_in[3];
    const float* W2  = (const float*)d_in[4];
    const float* b2  = (const float*)d_in[5];
    const float* S1  = (const float*)d_in[6];
    const float* sb1 = (const float*)d_in[7];
    const float* S2  = (const float*)d_in[8];
    const float* sb2 = (const float*)d_in[9];
    const float* S3  = (const float*)d_in[10];
    const float* sb3 = (const float*)d_in[11];
    const float* O   = (const float*)d_in[12];
    const float* ob  = (const float*)d_in[13];
    float* out = (float*)d_out;

    char* ws = (char*)d_ws;
    size_t off = 0;
    auto alloc = [&](size_t bytes) {
        void* p = ws + off;
        off += (bytes + 255) & ~(size_t)255;
        return p;
    };
    _Float16* x    = (_Float16*)alloc((size_t)kR * kCH * 2);        //  2.6 MB
    _Float16* h    = (_Float16*)alloc((size_t)kR * kINNER * 2);     // 10.5 MB
    _Float16* xe   = (_Float16*)alloc((size_t)kR * kXE * 2);        //  4.2 MB
    _Float16* W1t  = (_Float16*)alloc((size_t)kINNER * kCH * 2);    // 13.1 MB
    _Float16* W2t  = (_Float16*)alloc((size_t)kOUTC * kINNER * 2);  // 10.5 MB
    _Float16* Ot   = (_Float16*)alloc((size_t)kOUTC * kXE * 2);     //  4.2 MB
    _Float16* S3t  = (_Float16*)alloc((size_t)kOUTC * kE2 * 2);     //  0.5 MB
    _Float16* h2f  = (_Float16*)alloc((size_t)kR * kE2 * 2);        //  0.5 MB
    float*    P    = (float*)alloc((size_t)8 * kR * kOUTC * 4);     // 33.6 MB (split-8 partials)
    const size_t ztBytes = (size_t)kBS * kPIX * kCH * 2;            // 83.9 MB
    _Float16* zt  = (_Float16*)(ws + off);
    const bool useT = (off + ztBytes) <= ws_size;

    // 0) all prep (weight converts + size-MLP 1+2 + z transpose) in one launch
    hipLaunchKernelGGL(prep_all, dim3(useT ? kPrepAllEnd : kPrepMlpEnd), dim3(32, 8), 0,
                       stream, z, zt, W1, W2, O, S3, W1t, W2t, Ot, S3t,
                       bb, S1, sb1, S2, sb2, h2f);

    // 1) ROI-align features -> x (1024 x 1280 f16), consolidated weights
    if (useT) {
        hipLaunchKernelGGL(roi_gather_f16_v3, dim3(kCH / 256, kR), dim3(256), 0, stream,
                           zt, bb, x);
    } else {
        hipLaunchKernelGGL(roi_gather_direct, dim3(kR), dim3(256), 0, stream, z, bb, x);
    }

    // 2) dual fused GEMM: S3-embedding (64 blocks) + GEMM1 (320 blocks)
    hipLaunchKernelGGL(gemm_dual, dim3(64 + (kINNER / 128) * (kR / 128)), dim3(256), 0,
                       stream, h2f, S3t, sb3, xe + kOUTC, x, W1t, b1, h);

    // 3) xe[:, 0:1024] = h @ W2 + b2: split-K x8 (512 blocks = 2/CU, 20 k-steps)
    hipLaunchKernelGGL((gemm_f16_sk<8>), dim3(kOUTC / 128, kR / 128, 8), dim3(256), 0,
                       stream, h, W2t, P, kINNER);
    hipLaunchKernelGGL((reduce_splitk<false, true, 8>),
                       dim3((size_t)kR * kOUTC / 1024), dim3(256), 0, stream,
                       P, b2, xe, kOUTC, kXE);

    // 4) out = xe @ O + ob: split-K x8 (512 blocks = 2/CU, 8 k-steps)
    hipLaunchKernelGGL((gemm_f16_sk<8>), dim3(kOUTC / 128, kR / 128, 8), dim3(256), 0,
                       stream, xe, Ot, P, kXE);
    hipLaunchKernelGGL((reduce_splitk<false, false, 8>),
                       dim3((size_t)kR * kOUTC / 1024), dim3(256), 0, stream,
                       P, ob, out, kOUTC, kOUTC);
}

// Round 7
// 419.621 us; speedup vs baseline: 1.1780x; 1.0106x over previous
//
#include <hip/hip_runtime.h>

// Problem constants
static constexpr int kBS    = 8;
static constexpr int kNROI  = 128;
static constexpr int kR     = kBS * kNROI;   // 1024 rows
static constexpr int kCH    = 1280;
static constexpr int kH     = 64;
static constexpr int kW     = 64;
static constexpr int kPIX   = kH * kW;       // 4096
static constexpr int kINNER = 5120;
static constexpr int kOUTC  = 1024;
static constexpr int kXE    = 2 * kOUTC;     // 2048 concat width
static constexpr int kE2    = 256;           // size-MLP hidden 2

typedef _Float16 half8 __attribute__((ext_vector_type(8)));   // f16x8 MFMA A/B frag
typedef float floatx4 __attribute__((ext_vector_type(4)));    // MFMA C/D frag

// Async global->LDS 16B copy. LDS dest must be wave-uniform base + lane*16,
// which our chunk-index==threadIdx staging layout satisfies exactly.
__device__ __forceinline__ void gload_lds16(const _Float16* g, _Float16* l) {
    __builtin_amdgcn_global_load_lds(
        (const __attribute__((address_space(1))) void*)g,
        (__attribute__((address_space(3))) void*)l,
        16, 0, 0);
}

// ---------------------------------------------------------------------------
// PREP mega-kernel (vectorized): all independent prep work in ONE launch.
// Flat 256 threads. Block ranges:
//   [0, 13824)           : weight transpose+convert 32x32 tiles (W1, W2, O, S3)
//   [13824, 14080)       : size-MLP layers 1+2 (4 ROIs per block)
//   [14080, 14080+10240) : z transpose+convert, 64ch x 64px tiles, float4 loads
// ---------------------------------------------------------------------------
static constexpr int kPrepConvEnd = 13824;
static constexpr int kPrepMlpEnd  = 14080;
static constexpr int kPrepAllEnd  = 14080 + (kPIX / 64) * (kCH / 64) * kBS;  // 24320

__global__ __launch_bounds__(256) void prep_all(const float* __restrict__ z,
                                                _Float16* __restrict__ zt,
                                                const float* __restrict__ W1,
                                                const float* __restrict__ W2,
                                                const float* __restrict__ O,
                                                const float* __restrict__ S3,
                                                _Float16* __restrict__ W1t,
                                                _Float16* __restrict__ W2t,
                                                _Float16* __restrict__ Ot,
                                                _Float16* __restrict__ S3t,
                                                const float* __restrict__ bboxes,
                                                const float* __restrict__ S1,
                                                const float* __restrict__ sb1,
                                                const float* __restrict__ S2,
                                                const float* __restrict__ sb2,
                                                _Float16* __restrict__ h2f) {
    __shared__ float smem[64 * 65];   // 16.6 KB, reused by all branches
    const int bid = blockIdx.x;
    const int t   = threadIdx.x;      // 0..255

    if (bid < kPrepConvEnd) {
        // ---- weight convert+transpose: W (K x N) fp32 -> Wt (N x K) f16 ----
        const float* W; _Float16* Wt; int K, N, tile;
        if (bid < 6400)        { W = W1; Wt = W1t; K = kCH;    N = kINNER; tile = bid; }
        else if (bid < 11520)  { W = W2; Wt = W2t; K = kINNER; N = kOUTC;  tile = bid - 6400; }
        else if (bid < 13568)  { W = O;  Wt = Ot;  K = kXE;    N = kOUTC;  tile = bid - 11520; }
        else                   { W = S3; Wt = S3t; K = kE2;    N = kOUTC;  tile = bid - 13568; }
        const int nt = N / 32;
        const int n0 = (tile % nt) * 32;
        const int k0 = (tile / nt) * 32;
        {   // load 32x32 floats as 256 float4 (row = k-local, col = n-local)
            const int row = t >> 3;          // 0..31
            const int c4  = (t & 7) * 4;     // 0..28
            const float4 v = *(const float4*)&W[(size_t)(k0 + row) * N + n0 + c4];
            float* tl = smem + row * 33 + c4;
            tl[0] = v.x; tl[1] = v.y; tl[2] = v.z; tl[3] = v.w;
        }
        __syncthreads();
        {   // transposed store: 4 k packed per thread -> uint2 (8B)
            const int n  = t >> 3;           // 0..31
            const int k4 = (t & 7) * 4;      // 0..28
            union { _Float16 h[4]; uint2 u; } pk;
#pragma unroll
            for (int j = 0; j < 4; ++j) pk.h[j] = (_Float16)smem[(k4 + j) * 33 + n];
            *(uint2*)&Wt[(size_t)(n0 + n) * K + k0 + k4] = pk.u;
        }
    } else if (bid < kPrepMlpEnd) {
        // ---- size-MLP layers 1+2: 2 -> 64 -> 256, 4 rows/block ----
        const int r0 = (bid - kPrepConvEnd) * 4;
        float* sz = smem;             // [4][2]
        float* h1 = smem + 8;         // [4][64]
        if (t < 8) {
            const int row = t >> 1;
            const int c   = t & 1;
            const float* bb = bboxes + (size_t)(r0 + row) * 4;
            sz[row * 2 + c] = (c == 0) ? (bb[3] - bb[1]) : (bb[2] - bb[0]);
        }
        __syncthreads();
        {   // layer 1: 4 rows x 64 = 256 items, one per thread
            const int row = t >> 6;
            const int j   = t & 63;
            const float v = sz[row * 2] * S1[j] + sz[row * 2 + 1] * S1[64 + j] + sb1[j];
            h1[row * 64 + j] = fmaxf(v, 0.0f);
        }
        __syncthreads();
        {   // layer 2: j = t, 4 rows register-blocked
            float acc[4];
            const float b = sb2[t];
#pragma unroll
            for (int row = 0; row < 4; ++row) acc[row] = b;
#pragma unroll 16
            for (int k = 0; k < 64; ++k) {
                const float w = S2[k * 256 + t];
#pragma unroll
                for (int row = 0; row < 4; ++row) acc[row] += h1[row * 64 + k] * w;
            }
#pragma unroll
            for (int row = 0; row < 4; ++row)
                h2f[(size_t)(r0 + row) * kE2 + t] = (_Float16)fmaxf(acc[row], 0.0f);
        }
    } else {
        // ---- z transpose+convert: 64ch x 64px tile, float4 loads ----
        const int tb   = bid - kPrepMlpEnd;
        const int perB = (kPIX / 64) * (kCH / 64);   // 64 * 20 = 1280
        const int b    = tb / perB;
        const int rem  = tb - b * perB;
        const int p0 = (rem % (kPIX / 64)) * 64;
        const int c0 = (rem / (kPIX / 64)) * 64;
        const float* zb = z + (size_t)b * kCH * kPIX;
        _Float16* ztb = zt + (size_t)b * kPIX * kCH;
        // load: 64 ch-rows x 64 px = 1024 float4, 4 per thread (1 KB/wave-instr)
#pragma unroll
        for (int i = 0; i < 4; ++i) {
            const int idx = t + i * 256;      // 0..1023
            const int row = idx >> 4;         // ch-local 0..63
            const int c4  = (idx & 15) * 4;   // px-local 0..60
            const float4 v = *(const float4*)&zb[(size_t)(c0 + row) * kPIX + p0 + c4];
            float* tl = smem + row * 65 + c4;
            tl[0] = v.x; tl[1] = v.y; tl[2] = v.z; tl[3] = v.w;
        }
        __syncthreads();
        // store: per pixel 64 ch f16; 4 ch packed per thread -> uint2 (8B)
#pragma unroll
        for (int i = 0; i < 4; ++i) {
            const int p  = (t >> 4) + i * 16; // px-local 0..63
            const int c4 = (t & 15) * 4;      // ch-local 0..60
            union { _Float16 h[4]; uint2 u; } pk;
#pragma unroll
            for (int j = 0; j < 4; ++j) pk.h[j] = (_Float16)smem[(c4 + j) * 65 + p];
            *(uint2*)(ztb + (size_t)(p0 + p) * kCH + c0 + c4) = pk.u;
        }
    }
}

// ---------------------------------------------------------------------------
// Consolidated ROI weights: distinct pixel rows/cols with summed separable
// weights (verified round 6).
// ---------------------------------------------------------------------------
struct RoiW {
    int   ymin, xmin, nyd, nxd;
    float ywt[12], xwt[12];
    float invCount;
};

__device__ inline void build_wcons(const float* __restrict__ bboxes, int r, RoiW* L) {
    const float x1 = bboxes[r * 4 + 0] * 0.125f - 0.5f;
    const float y1 = bboxes[r * 4 + 1] * 0.125f - 0.5f;
    const float x2 = bboxes[r * 4 + 2] * 0.125f - 0.5f;
    const float y2 = bboxes[r * 4 + 3] * 0.125f - 0.5f;
    const float rw = x2 - x1, rh = y2 - y1;
    const float gwf = fminf(fmaxf(ceilf(rw), 1.0f), 8.0f);
    const float ghf = fminf(fmaxf(ceilf(rh), 1.0f), 8.0f);
    const int gw = (int)gwf, gh = (int)ghf;
    L->invCount = 1.0f / (gwf * ghf);

#pragma unroll
    for (int i = 0; i < 12; ++i) { L->ywt[i] = 0.0f; L->xwt[i] = 0.0f; }

    int ymin = 0, last = 0;
    for (int g = 0; g < gh; ++g) {
        const float c   = y1 + ((float)g + 0.5f) * rh / ghf;
        const bool oob  = (c < -1.0f) || (c > 64.0f);
        const float cc  = fmaxf(c, 0.0f);
        const float lo0 = floorf(cc);
        const bool hic  = (lo0 >= 63.0f);
        const int lo    = (int)fminf(lo0, 63.0f);
        const int hi    = (int)fminf(lo0 + 1.0f, 63.0f);
        const float fr  = hic ? 0.0f : (cc - lo0);
        const float m   = oob ? 0.0f : 1.0f;
        if (g == 0) ymin = lo;
        const int il = min(lo - ymin, 11);
        const int ih = min(hi - ymin, 11);
        L->ywt[il] += m * (1.0f - fr);
        L->ywt[ih] += m * fr;
        last = hi;
    }
    L->ymin = ymin;
    L->nyd  = min(last - ymin + 1, 12);

    int xmin = 0; last = 0;
    for (int g = 0; g < gw; ++g) {
        const float c   = x1 + ((float)g + 0.5f) * rw / gwf;
        const bool oob  = (c < -1.0f) || (c > 64.0f);
        const float cc  = fmaxf(c, 0.0f);
        const float lo0 = floorf(cc);
        const bool hic  = (lo0 >= 63.0f);
        const int lo    = (int)fminf(lo0, 63.0f);
        const int hi    = (int)fminf(lo0 + 1.0f, 63.0f);
        const float fr  = hic ? 0.0f : (cc - lo0);
        const float m   = oob ? 0.0f : 1.0f;
        if (g == 0) xmin = lo;
        const int il = min(lo - xmin, 11);
        const int ih = min(hi - xmin, 11);
        L->xwt[il] += m * (1.0f - fr);
        L->xwt[ih] += m * fr;
        last = hi;
    }
    L->xmin = xmin;
    L->nxd  = min(last - xmin + 1, 12);
}

// ---------------------------------------------------------------------------
// ROI gather v3 from channels-last f16 zt -> f16 x (1024 x 1280).
// Grid (5, kR). Consolidated point list (<=144, avg ~30). LDS tree-reduce.
// ---------------------------------------------------------------------------
__global__ __launch_bounds__(256) void roi_gather_f16_v3(const _Float16* __restrict__ zt,
                                                         const float* __restrict__ bboxes,
                                                         _Float16* __restrict__ x) {
    const int r  = blockIdx.y;
    const int b  = r >> 7;
    const int cg = blockIdx.x * 32;    // base chunk (c8 units) of this block
    const int t  = threadIdx.x;
    __shared__ RoiW L;
    __shared__ int   off[144];
    __shared__ float wt[144];
    __shared__ float accs[8][32][9];   // [pg][chunk][ch] (+1 pad col)
    if (t == 0) build_wcons(bboxes, r, &L);
    __syncthreads();
    const int np = L.nyd * L.nxd;      // <= 144
    if (t < np) {
        const int iy = t / L.nxd;
        const int ix = t - iy * L.nxd;
        off[t] = ((L.ymin + iy) * kW + (L.xmin + ix)) * kCH;
        wt[t]  = L.ywt[iy] * L.xwt[ix];
    }
    __syncthreads();
    const int lc = t & 31;
    const int pg = t >> 5;
    const _Float16* base = zt + (size_t)b * kPIX * kCH + (size_t)(cg + lc) * 8;
    float a[8] = {0.f, 0.f, 0.f, 0.f, 0.f, 0.f, 0.f, 0.f};
    for (int p = pg; p < np; p += 8) {
        const float w = wt[p];
        const half8 v = *(const half8*)(base + off[p]);
#pragma unroll
        for (int q = 0; q < 8; ++q) a[q] += w * (float)v[q];
    }
#pragma unroll
    for (int q = 0; q < 8; ++q) accs[pg][lc][q] = a[q];
    __syncthreads();
    // reduce: thread t -> chunk rc = t>>3, channel ch = t&7 (contiguous store)
    const int rc = t >> 3, ch = t & 7;
    float s = 0.f;
#pragma unroll
    for (int g = 0; g < 8; ++g) s += accs[g][rc][ch];
    x[(size_t)r * kCH + (size_t)(cg + rc) * 8 + ch] = (_Float16)(s * L.invCount);
}

// Fallback: gather directly from fp32 z (b,c,H,W) -> f16 x (consolidated too)
__global__ __launch_bounds__(256) void roi_gather_direct(const float* __restrict__ z,
                                                         const float* __restrict__ bboxes,
                                                         _Float16* __restrict__ x) {
    const int r = blockIdx.x;
    const int b = r >> 7;
    __shared__ RoiW L;
    if (threadIdx.x == 0) build_wcons(bboxes, r, &L);
    __syncthreads();
    const float ic = L.invCount;
    const float* zb = z + (size_t)b * kCH * kPIX;
    for (int c = threadIdx.x; c < kCH; c += 256) {
        const float* zc = zb + (size_t)c * kPIX;
        float acc = 0.f;
        for (int iy = 0; iy < L.nyd; ++iy) {
            const float wy = L.ywt[iy];
            const int base = (L.ymin + iy) * kW + L.xmin;
            for (int ix = 0; ix < L.nxd; ++ix)
                acc += wy * L.xwt[ix] * zc[base + ix];
        }
        x[(size_t)r * kCH + c] = (_Float16)(acc * ic);
    }
}

// ---------------------------------------------------------------------------
// f16 MFMA GEMM (NT), 128x128 tile, BK=32, 256 threads = 4 waves.
// Double-buffered global_load_lds staging (verified round 3/5).
// Split-K partial (blockIdx.z), raw fp32 plane store -> P.
// ---------------------------------------------------------------------------
template <int NSPLIT>
__global__ __launch_bounds__(256) void gemm_f16_sk(const _Float16* __restrict__ A,
                                                   const _Float16* __restrict__ Bt,
                                                   float* __restrict__ P,
                                                   int Kfull) {
    __shared__ _Float16 As[2][128 * 32];
    __shared__ _Float16 Bs[2][128 * 32];
    const int t    = threadIdx.x;
    const int lane = t & 63;
    const int wave = t >> 6;
    const int m0 = blockIdx.y * 128, n0 = blockIdx.x * 128;
    const int Ksplit = Kfull / NSPLIT;
    const int s  = blockIdx.z;
    const int Nn = gridDim.x * 128;
    const int Mm = gridDim.y * 128;

    const int c0 = t, c1 = t + 256;
    const _Float16* Ag0 = A + (size_t)(m0 + (c0 >> 2)) * Kfull + (c0 & 3) * 8 + s * Ksplit;
    const _Float16* Ag1 = A + (size_t)(m0 + (c1 >> 2)) * Kfull + (c1 & 3) * 8 + s * Ksplit;
    const _Float16* Bg0 = Bt + (size_t)(n0 + (c0 >> 2)) * Kfull + (c0 & 3) * 8 + s * Ksplit;
    const _Float16* Bg1 = Bt + (size_t)(n0 + (c1 >> 2)) * Kfull + (c1 & 3) * 8 + s * Ksplit;

    const int wm = (wave >> 1) * 64;
    const int wn = (wave & 1) * 64;
    const int fm = lane & 15;
    const int kq = (lane >> 4) * 8;

    floatx4 acc[4][4];
#pragma unroll
    for (int i = 0; i < 4; ++i)
#pragma unroll
        for (int j = 0; j < 4; ++j) acc[i][j] = (floatx4){0.f, 0.f, 0.f, 0.f};

    const int nsteps = Ksplit / 32;
    gload_lds16(Ag0, &As[0][c0 * 8]);
    gload_lds16(Ag1, &As[0][c1 * 8]);
    gload_lds16(Bg0, &Bs[0][c0 * 8]);
    gload_lds16(Bg1, &Bs[0][c1 * 8]);
    __syncthreads();

    for (int ks = 0; ks < nsteps; ++ks) {
        const int cur = ks & 1;
        if (ks + 1 < nsteps) {
            const int kn = (ks + 1) * 32;
            gload_lds16(Ag0 + kn, &As[cur ^ 1][c0 * 8]);
            gload_lds16(Ag1 + kn, &As[cur ^ 1][c1 * 8]);
            gload_lds16(Bg0 + kn, &Bs[cur ^ 1][c0 * 8]);
            gload_lds16(Bg1 + kn, &Bs[cur ^ 1][c1 * 8]);
        }
        half8 af[4], bfv[4];
#pragma unroll
        for (int i = 0; i < 4; ++i)
            af[i] = *(const half8*)&As[cur][(wm + i * 16 + fm) * 32 + kq];
#pragma unroll
        for (int j = 0; j < 4; ++j)
            bfv[j] = *(const half8*)&Bs[cur][(wn + j * 16 + fm) * 32 + kq];
#pragma unroll
        for (int i = 0; i < 4; ++i)
#pragma unroll
            for (int j = 0; j < 4; ++j)
                acc[i][j] = __builtin_amdgcn_mfma_f32_16x16x32_f16(af[i], bfv[j], acc[i][j], 0, 0, 0);
        __syncthreads();
    }

    float* Pp = P + (size_t)s * Mm * Nn;
    const int qr = (lane >> 4) * 4;
#pragma unroll
    for (int j = 0; j < 4; ++j) {
        const int col = n0 + wn + j * 16 + fm;
#pragma unroll
        for (int i = 0; i < 4; ++i) {
            const int row = m0 + wm + i * 16 + qr;
#pragma unroll
            for (int rr = 0; rr < 4; ++rr)
                Pp[(size_t)(row + rr) * Nn + col] = acc[i][j][rr];
        }
    }
}

// ---------------------------------------------------------------------------
// DUAL fused GEMM: S3-embedding GEMM (64 blocks) + GEMM1 (320 blocks) in one
// launch (verified round 6).
// ---------------------------------------------------------------------------
__global__ __launch_bounds__(256) void gemm_dual(const _Float16* __restrict__ h2f,
                                                 const _Float16* __restrict__ S3t,
                                                 const float* __restrict__ sb3,
                                                 _Float16* __restrict__ xeR,
                                                 const _Float16* __restrict__ x,
                                                 const _Float16* __restrict__ W1t,
                                                 const float* __restrict__ b1,
                                                 _Float16* __restrict__ h) {
    __shared__ _Float16 As[2][128 * 32];
    __shared__ _Float16 Bs[2][128 * 32];
    const int bid = blockIdx.x;
    const _Float16* A; const _Float16* Bt; const float* bias; _Float16* Out;
    int Kfull, ldc, nbn, tile; bool relu;
    if (bid < 64) {
        A = h2f; Bt = S3t; bias = sb3; Out = xeR;
        Kfull = kE2; ldc = kXE; relu = false; nbn = kOUTC / 128; tile = bid;
    } else {
        A = x; Bt = W1t; bias = b1; Out = h;
        Kfull = kCH; ldc = kINNER; relu = true; nbn = kINNER / 128; tile = bid - 64;
    }
    const int n0 = (tile % nbn) * 128;
    const int m0 = (tile / nbn) * 128;

    const int t    = threadIdx.x;
    const int lane = t & 63;
    const int wave = t >> 6;

    const int c0 = t, c1 = t + 256;
    const _Float16* Ag0 = A + (size_t)(m0 + (c0 >> 2)) * Kfull + (c0 & 3) * 8;
    const _Float16* Ag1 = A + (size_t)(m0 + (c1 >> 2)) * Kfull + (c1 & 3) * 8;
    const _Float16* Bg0 = Bt + (size_t)(n0 + (c0 >> 2)) * Kfull + (c0 & 3) * 8;
    const _Float16* Bg1 = Bt + (size_t)(n0 + (c1 >> 2)) * Kfull + (c1 & 3) * 8;

    const int wm = (wave >> 1) * 64;
    const int wn = (wave & 1) * 64;
    const int fm = lane & 15;
    const int kq = (lane >> 4) * 8;

    floatx4 acc[4][4];
#pragma unroll
    for (int i = 0; i < 4; ++i)
#pragma unroll
        for (int j = 0; j < 4; ++j) acc[i][j] = (floatx4){0.f, 0.f, 0.f, 0.f};

    const int nsteps = Kfull / 32;
    gload_lds16(Ag0, &As[0][c0 * 8]);
    gload_lds16(Ag1, &As[0][c1 * 8]);
    gload_lds16(Bg0, &Bs[0][c0 * 8]);
    gload_lds16(Bg1, &Bs[0][c1 * 8]);
    __syncthreads();

    for (int ks = 0; ks < nsteps; ++ks) {
        const int cur = ks & 1;
        if (ks + 1 < nsteps) {
            const int kn = (ks + 1) * 32;
            gload_lds16(Ag0 + kn, &As[cur ^ 1][c0 * 8]);
            gload_lds16(Ag1 + kn, &As[cur ^ 1][c1 * 8]);
            gload_lds16(Bg0 + kn, &Bs[cur ^ 1][c0 * 8]);
            gload_lds16(Bg1 + kn, &Bs[cur ^ 1][c1 * 8]);
        }
        half8 af[4], bfv[4];
#pragma unroll
        for (int i = 0; i < 4; ++i)
            af[i] = *(const half8*)&As[cur][(wm + i * 16 + fm) * 32 + kq];
#pragma unroll
        for (int j = 0; j < 4; ++j)
            bfv[j] = *(const half8*)&Bs[cur][(wn + j * 16 + fm) * 32 + kq];
#pragma unroll
        for (int i = 0; i < 4; ++i)
#pragma unroll
            for (int j = 0; j < 4; ++j)
                acc[i][j] = __builtin_amdgcn_mfma_f32_16x16x32_f16(af[i], bfv[j], acc[i][j], 0, 0, 0);
        __syncthreads();
    }

    // Epilogue: bias (+relu) -> f16 at ldc. C/D: col = lane&15, row = (lane>>4)*4+rr
    const int qr = (lane >> 4) * 4;
#pragma unroll
    for (int j = 0; j < 4; ++j) {
        const int col = n0 + wn + j * 16 + fm;
        const float bv = bias[col];
#pragma unroll
        for (int i = 0; i < 4; ++i) {
            const int row = m0 + wm + i * 16 + qr;
#pragma unroll
            for (int rr = 0; rr < 4; ++rr) {
                float v = acc[i][j][rr] + bv;
                if (relu) v = fmaxf(v, 0.f);
                Out[(size_t)(row + rr) * ldc + col] = (_Float16)v;
            }
        }
    }
}

// ---------------------------------------------------------------------------
// Split-K reduce + bias + (relu) + convert.
// ---------------------------------------------------------------------------
template <bool RELU, bool F16OUT, int NSPLIT>
__global__ __launch_bounds__(256) void reduce_splitk(const float* __restrict__ P,
                                                     const float* __restrict__ bias,
                                                     void* __restrict__ Cout,
                                                     int Nn, int ldc) {
    const size_t idx = ((size_t)blockIdx.x * 256 + threadIdx.x) * 4;
    const size_t MN  = (size_t)gridDim.x * 1024;
    const int m = (int)(idx / (size_t)Nn);
    const int n = (int)(idx % (size_t)Nn);
    float4 acc = *(const float4*)(P + idx);
#pragma unroll
    for (int s = 1; s < NSPLIT; ++s) {
        const float4 v = *(const float4*)(P + (size_t)s * MN + idx);
        acc.x += v.x; acc.y += v.y; acc.z += v.z; acc.w += v.w;
    }
    const float4 b4 = *(const float4*)(bias + n);
    acc.x += b4.x; acc.y += b4.y; acc.z += b4.z; acc.w += b4.w;
    if (RELU) {
        acc.x = fmaxf(acc.x, 0.f); acc.y = fmaxf(acc.y, 0.f);
        acc.z = fmaxf(acc.z, 0.f); acc.w = fmaxf(acc.w, 0.f);
    }
    if (F16OUT) {
        union { _Float16 h[4]; uint2 u; } pk;
        pk.h[0] = (_Float16)acc.x; pk.h[1] = (_Float16)acc.y;
        pk.h[2] = (_Float16)acc.z; pk.h[3] = (_Float16)acc.w;
        *(uint2*)((_Float16*)Cout + (size_t)m * ldc + n) = pk.u;
    } else {
        *(float4*)((float*)Cout + (size_t)m * ldc + n) = acc;
    }
}

// ---------------------------------------------------------------------------
extern "C" void kernel_launch(void* const* d_in, const int* in_sizes, int n_in,
                              void* d_out, int out_size, void* d_ws, size_t ws_size,
                              hipStream_t stream) {
    (void)in_sizes; (void)n_in; (void)out_size;
    const float* z   = (const float*)d_in[0];
    const float* bb  = (const float*)d_in[1];
    const float* W1  = (const float*)d_in[2];
    const float* b1  = (const float*)d_in[3];
    const float* W2  = (const float*)d_in[4];
    const float* b2  = (const float*)d_in[5];
    const float* S1  = (const float*)d_in[6];
    const float* sb1 = (const float*)d_in[7];
    const float* S2  = (const float*)d_in[8];
    const float* sb2 = (const float*)d_in[9];
    const float* S3  = (const float*)d_in[10];
    const float* sb3 = (const float*)d_in[11];
    const float* O   = (const float*)d_in[12];
    const float* ob  = (const float*)d_in[13];
    float* out = (float*)d_out;

    char* ws = (char*)d_ws;
    size_t off = 0;
    auto alloc = [&](size_t bytes) {
        void* p = ws + off;
        off += (bytes + 255) & ~(size_t)255;
        return p;
    };
    _Float16* x    = (_Float16*)alloc((size_t)kR * kCH * 2);        //  2.6 MB
    _Float16* h    = (_Float16*)alloc((size_t)kR * kINNER * 2);     // 10.5 MB
    _Float16* xe   = (_Float16*)alloc((size_t)kR * kXE * 2);        //  4.2 MB
    _Float16* W1t  = (_Float16*)alloc((size_t)kINNER * kCH * 2);    // 13.1 MB
    _Float16* W2t  = (_Float16*)alloc((size_t)kOUTC * kINNER * 2);  // 10.5 MB
    _Float16* Ot   = (_Float16*)alloc((size_t)kOUTC * kXE * 2);     //  4.2 MB
    _Float16* S3t  = (_Float16*)alloc((size_t)kOUTC * kE2 * 2);     //  0.5 MB
    _Float16* h2f  = (_Float16*)alloc((size_t)kR * kE2 * 2);        //  0.5 MB
    float*    P    = (float*)alloc((size_t)8 * kR * kOUTC * 4);     // 33.6 MB (split-8 partials)
    const size_t ztBytes = (size_t)kBS * kPIX * kCH * 2;            // 83.9 MB
    _Float16* zt  = (_Float16*)(ws + off);
    const bool useT = (off + ztBytes) <= ws_size;

    // 0) all prep (weight converts + size-MLP 1+2 + z transpose) in one launch
    hipLaunchKernelGGL(prep_all, dim3(useT ? kPrepAllEnd : kPrepMlpEnd), dim3(256), 0,
                       stream, z, zt, W1, W2, O, S3, W1t, W2t, Ot, S3t,
                       bb, S1, sb1, S2, sb2, h2f);

    // 1) ROI-align features -> x (1024 x 1280 f16), consolidated weights
    if (useT) {
        hipLaunchKernelGGL(roi_gather_f16_v3, dim3(kCH / 256, kR), dim3(256), 0, stream,
                           zt, bb, x);
    } else {
        hipLaunchKernelGGL(roi_gather_direct, dim3(kR), dim3(256), 0, stream, z, bb, x);
    }

    // 2) dual fused GEMM: S3-embedding (64 blocks) + GEMM1 (320 blocks)
    hipLaunchKernelGGL(gemm_dual, dim3(64 + (kINNER / 128) * (kR / 128)), dim3(256), 0,
                       stream, h2f, S3t, sb3, xe + kOUTC, x, W1t, b1, h);

    // 3) xe[:, 0:1024] = h @ W2 + b2: split-K x8 (512 blocks = 2/CU, 20 k-steps)
    hipLaunchKernelGGL((gemm_f16_sk<8>), dim3(kOUTC / 128, kR / 128, 8), dim3(256), 0,
                       stream, h, W2t, P, kINNER);
    hipLaunchKernelGGL((reduce_splitk<false, true, 8>),
                       dim3((size_t)kR * kOUTC / 1024), dim3(256), 0, stream,
                       P, b2, xe, kOUTC, kXE);

    // 4) out = xe @ O + ob: split-K x8 (512 blocks = 2/CU, 8 k-steps)
    hipLaunchKernelGGL((gemm_f16_sk<8>), dim3(kOUTC / 128, kR / 128, 8), dim3(256), 0,
                       stream, xe, Ot, P, kXE);
    hipLaunchKernelGGL((reduce_splitk<false, false, 8>),
                       dim3((size_t)kR * kOUTC / 1024), dim3(256), 0, stream,
                       P, ob, out, kOUTC, kOUTC);
}